// Round 1
// baseline (288.952 us; speedup 1.0000x reference)
//
#include <hip/hip_runtime.h>
#include <hip/hip_fp16.h>
#include <math.h>

#define NN 50000
#define NE 800000
#define FN 128
#define FE 32
#define HD 64
#define NB 49   // scan blocks: ceil(NN/1024)
#define GP ((NN + 127) / 128)   // proj blocks (128 rows each)
#define EB ((NE + 511) / 512)   // edge blocks, 512 edges each (2 per thread)

typedef unsigned long long u64;
typedef unsigned short u16;

// ---------------- K0: fold edge chains into v1,v2,v3 + zero deg --------------
__global__ void k_vecs_zero(const float* __restrict__ We1, const float* __restrict__ We2,
                            const float* __restrict__ We3, const float* __restrict__ ae1,
                            const float* __restrict__ ae2, const float* __restrict__ ae3,
                            float* __restrict__ v123, int* __restrict__ deg) {
  const int i = blockIdx.x * blockDim.x + threadIdx.x;
  if (i < NN) deg[i] = 0;
  if (blockIdx.x != 0) return;
  __shared__ float u2[HD], u3[HD], u23[HD];
  const int t = threadIdx.x;
  if (t < HD) {
    float s2 = 0.f, s3 = 0.f;
    for (int j = 0; j < HD; ++j) {
      s2 += We2[t * HD + j] * ae2[j];
      s3 += We3[t * HD + j] * ae3[j];
    }
    u2[t] = s2; u3[t] = s3;
  }
  __syncthreads();
  if (t < HD) {
    float s23 = 0.f;
    for (int j = 0; j < HD; ++j) s23 += We2[t * HD + j] * u3[j];
    u23[t] = s23;
  }
  __syncthreads();
  if (t < FE) {
    float a = 0.f, b = 0.f, c = 0.f;
    for (int j = 0; j < HD; ++j) {
      float w = We1[t * HD + j];
      a += w * ae1[j];
      b += w * u2[j];
      c += w * u23[j];
    }
    v123[t] = a; v123[32 + t] = b; v123[64 + t] = c;
  }
}

// ---------------- edge scalars -> 8B record ----------------------------------
__device__ __forceinline__ u64 make_trec(const float* __restrict__ eattr,
                                         const float* __restrict__ v123,
                                         int s, int e) {
  const float4* ea = (const float4*)(eattr + (size_t)e * FE);
  float a = 0.f, b = 0.f, c = 0.f;
#pragma unroll
  for (int q = 0; q < FE / 4; ++q) {
    float4 xv = ea[q];
    const float* v1 = v123 + q * 4;
    const float* v2 = v123 + 32 + q * 4;
    const float* v3 = v123 + 64 + q * 4;
    a += xv.x * v1[0] + xv.y * v1[1] + xv.z * v1[2] + xv.w * v1[3];
    b += xv.x * v2[0] + xv.y * v2[1] + xv.z * v2[2] + xv.w * v2[3];
    c += xv.x * v3[0] + xv.y * v3[1] + xv.z * v3[2] + xv.w * v3[3];
  }
  return (u64)(u16)s
       | ((u64)__half_as_ushort(__float2half_rn(a)) << 16)
       | ((u64)__half_as_ushort(__float2half_rn(b)) << 32)
       | ((u64)__half_as_ushort(__float2half_rn(c)) << 48);
}

// ---- k_edge: per-thread fused {deg atomic -> eattr stream -> rank store} ----
// 0 LDS, <=64 VGPR (32 waves/CU). Atomics are issued FIRST (oldest in vmcnt
// queue) so their device-scope round trip hides under 2x 128B eattr compute.
__global__ __launch_bounds__(256, 8) void k_edge(
    const int* __restrict__ srcA, const int* __restrict__ dstA,
    const float* __restrict__ eattr, const float* __restrict__ v123,
    int* __restrict__ deg, u16* __restrict__ rank, u64* __restrict__ trec) {
  const int t = threadIdx.x;
  const int base = blockIdx.x * 512;
  const int e0 = base + t;
  const int e1 = base + 256 + t;
  const bool ok0 = e0 < NE, ok1 = e1 < NE;

  int d0 = 0, d1 = 0, s0 = 0, s1 = 0;
  if (ok0) d0 = dstA[e0];
  if (ok1) d1 = dstA[e1];
  int r0 = 0, r1 = 0;
  if (ok0) r0 = atomicAdd(&deg[d0], 1);   // in flight during stream below
  if (ok1) r1 = atomicAdd(&deg[d1], 1);
  if (ok0) s0 = srcA[e0];
  if (ok1) s1 = srcA[e1];

  if (ok0) trec[e0] = make_trec(eattr, v123, s0, e0);
  if (ok1) trec[e1] = make_trec(eattr, v123, s1, e1);

  if (ok0) rank[e0] = (u16)r0;
  if (ok1) rank[e1] = (u16)r1;
}

// ---------------- 2-phase parallel scan --------------------------------------
__global__ __launch_bounds__(256) void k_scanA(const int* __restrict__ deg,
                                               int* __restrict__ bsum) {
  __shared__ int ws[4];
  const int t = threadIdx.x, lane = t & 63, wid = t >> 6;
  const int i0 = blockIdx.x * 1024 + t * 4;
  int s = 0;
#pragma unroll
  for (int j = 0; j < 4; ++j) {
    int i = i0 + j;
    if (i < NN) s += deg[i];
  }
#pragma unroll
  for (int off = 32; off; off >>= 1) s += __shfl_xor(s, off);
  if (lane == 0) ws[wid] = s;
  __syncthreads();
  if (t == 0) bsum[blockIdx.x] = ws[0] + ws[1] + ws[2] + ws[3];
}

__global__ __launch_bounds__(256) void k_scanB(const int* __restrict__ deg,
                                               const int* __restrict__ bsum,
                                               int* __restrict__ row_ptr) {
  __shared__ int blockOff;
  __shared__ int wOff[4];
  const int b = blockIdx.x;
  const int t = threadIdx.x, lane = t & 63, wid = t >> 6;
  if (t < 64) {
    int v = (t < NB) ? bsum[t] : 0;
    int p = v;
#pragma unroll
    for (int off = 1; off < 64; off <<= 1) {
      int u = __shfl_up(p, off);
      if (lane >= off) p += u;
    }
    if (t == b) blockOff = p - v;
    if (b == 0 && t == NB - 1) row_ptr[NN] = p;
  }
  __syncthreads();
  const int i0 = b * 1024 + t * 4;
  int v[4];
#pragma unroll
  for (int j = 0; j < 4; ++j) {
    int i = i0 + j;
    v[j] = (i < NN) ? deg[i] : 0;
  }
  int s = v[0] + v[1] + v[2] + v[3];
  int p = s;
#pragma unroll
  for (int off = 1; off < 64; off <<= 1) {
    int u = __shfl_up(p, off);
    if (lane >= off) p += u;
  }
  if (lane == 63) wOff[wid] = p;
  __syncthreads();
  int woff = 0;
  for (int wq = 0; wq < wid; ++wq) woff += wOff[wq];
  int excl = blockOff + woff + (p - s);
#pragma unroll
  for (int j = 0; j < 4; ++j) {
    int i = i0 + j;
    if (i < NN) row_ptr[i] = excl;
    excl += v[j];
  }
}

// ---- mega2: [0,GP) LDS-free layer-1 GEMM | rest: CSR scatter (2 edges/thr) --
// GEMM reads x via 16-lane-broadcast float4 loads (L1-served) and W as fp32
// float4 (contiguous 256B/wave, L1-resident 32KB): no LDS -> no 32KB tax on
// the scatter blocks, no stage barriers. Scatter overlaps the GEMM on-CU.
__global__ __launch_bounds__(256, 6) void k_gemm_scatter(
    const float* __restrict__ x, const float* __restrict__ W,
    const float* __restrict__ asv, const float* __restrict__ adv,
    __half* __restrict__ xph, float* __restrict__ ssrc, float* __restrict__ sdst,
    const int* __restrict__ dstA, const u16* __restrict__ rank,
    const int* __restrict__ row_ptr, const u64* __restrict__ trec,
    u64* __restrict__ aos) {
  const int t = threadIdx.x;
  if (blockIdx.x >= GP) {
    const int base = (blockIdx.x - GP) * 512;
    const int e0 = base + t;
    const int e1 = base + 256 + t;
    if (e0 < NE) aos[row_ptr[dstA[e0]] + (int)rank[e0]] = trec[e0];
    if (e1 < NE) aos[row_ptr[dstA[e1]] + (int)rank[e1]] = trec[e1];
    return;
  }
  // ---- proj part (F = FN = 128, fp32 x, fp32 W) ----
  const int w = t >> 6, l = t & 63;
  const int g = w * 4 + (l >> 4);
  const int rr = g * 8;
  const int c0 = (l & 15) * 4;
  const int row0 = blockIdx.x * 128;

  int xoff[8];   // element offsets, tail rows clamped to a valid row (stores guarded)
#pragma unroll
  for (int i = 0; i < 8; ++i) {
    int gr = row0 + rr + i;
    xoff[i] = (gr < NN ? gr : NN - 1) * FN;
  }

  float acc[8][4];
#pragma unroll
  for (int i = 0; i < 8; ++i)
#pragma unroll
    for (int j = 0; j < 4; ++j) acc[i][j] = 0.f;

  for (int k = 0; k < FN; k += 4) {
    float wv[4][4];
#pragma unroll
    for (int kk = 0; kk < 4; ++kk) {
      float4 wq = *(const float4*)(W + (k + kk) * HD + c0);
      wv[kk][0] = wq.x; wv[kk][1] = wq.y; wv[kk][2] = wq.z; wv[kk][3] = wq.w;
    }
#pragma unroll
    for (int i = 0; i < 8; ++i) {
      float4 a = *(const float4*)(x + xoff[i] + k);
#pragma unroll
      for (int j = 0; j < 4; ++j)
        acc[i][j] += a.x * wv[0][j] + a.y * wv[1][j] + a.z * wv[2][j] + a.w * wv[3][j];
    }
  }

  float as4[4], ad4[4];
#pragma unroll
  for (int j = 0; j < 4; ++j) { as4[j] = asv[c0 + j]; ad4[j] = adv[c0 + j]; }
#pragma unroll
  for (int i = 0; i < 8; ++i) {
    int gr = row0 + rr + i;
    float ps = 0.f, pd = 0.f;
#pragma unroll
    for (int j = 0; j < 4; ++j) {
      ps += acc[i][j] * as4[j];
      pd += acc[i][j] * ad4[j];
    }
#pragma unroll
    for (int off = 1; off < 16; off <<= 1) {
      ps += __shfl_xor(ps, off);
      pd += __shfl_xor(pd, off);
    }
    if (gr < NN) {
      union { __half2 h2[2]; float2 f2; } u;
      u.h2[0] = __floats2half2_rn(acc[i][0], acc[i][1]);
      u.h2[1] = __floats2half2_rn(acc[i][2], acc[i][3]);
      *(float2*)(xph + (size_t)gr * HD + c0) = u.f2;
      if ((l & 15) == 0) { ssrc[gr] = ps; sdst[gr] = pd; }
    }
  }
}

// ------ fused: segment-softmax aggregate + NEXT-layer projection -------------
// 8 nodes per wave, 8 lanes per node (R11/R14 winning layout), chunk=16.
template <int TSEL>
__global__ __launch_bounds__(256) void k_agg_proj(
    const int* __restrict__ row_ptr, const u64* __restrict__ aos,
    const __half* __restrict__ xin, const float* __restrict__ ssrc_in,
    const float* __restrict__ sdst_in, const float* __restrict__ bias,
    const float* __restrict__ Wn, const float* __restrict__ asn,
    const float* __restrict__ adn, __half* __restrict__ xout,
    float* __restrict__ ssrc_out, float* __restrict__ sdst_out) {
  __shared__ __half swh[HD * HD];  // 8 KB, next-layer W in fp16
  const int t = threadIdx.x;
  for (int i = t; i < HD * HD; i += 256) swh[i] = __float2half_rn(Wn[i]);

  const int gw = (blockIdx.x * blockDim.x + t) >> 6;
  const int lane = t & 63;
  const int g = lane >> 3;
  const int q = lane & 7;
  const int n = gw * 8 + g;
  const bool act = n < NN;
  int beg = 0, end = 0;
  float sd = 0.f;
  if (act) { beg = row_ptr[n]; end = row_ptr[n + 1]; sd = sdst_in[n]; }

  float dsum = 0.f;
  float4 o0 = make_float4(0.f, 0.f, 0.f, 0.f);
  float4 o1 = make_float4(0.f, 0.f, 0.f, 0.f);
  for (int base = beg; base < end; base += 16) {
    const int p0 = base + q, p1 = base + 8 + q;
    float pe0 = 0.f, pe1 = 0.f;
    int s0 = 0, s1 = 0;
    if (p0 < end) {
      u64 r = aos[p0];
      s0 = (int)(r & 0xFFFFu);
      float tt = __half2float(__ushort_as_half((u16)((r >> (16 * TSEL)) & 0xFFFFu)));
      float raw = ssrc_in[s0] + sd + tt;
      raw = raw > 0.f ? raw : 0.2f * raw;
      pe0 = __expf(raw);
    }
    if (p1 < end) {
      u64 r = aos[p1];
      s1 = (int)(r & 0xFFFFu);
      float tt = __half2float(__ushort_as_half((u16)((r >> (16 * TSEL)) & 0xFFFFu)));
      float raw = ssrc_in[s1] + sd + tt;
      raw = raw > 0.f ? raw : 0.2f * raw;
      pe1 = __expf(raw);
    }
    dsum += pe0 + pe1;
#pragma unroll
    for (int j = 0; j < 8; ++j) {
      const int sl = g * 8 + j;
      float pa = __shfl(pe0, sl);
      int sa = __shfl(s0, sl);
      float pb = __shfl(pe1, sl);
      int sb = __shfl(s1, sl);
      union { float4 f4; __half2 h2[4]; } ua, ub;
      ua.f4 = ((const float4*)(xin + (size_t)sa * HD))[q];
      ub.f4 = ((const float4*)(xin + (size_t)sb * HD))[q];
      float2 a0 = __half22float2(ua.h2[0]);
      float2 a1 = __half22float2(ua.h2[1]);
      float2 a2 = __half22float2(ua.h2[2]);
      float2 a3 = __half22float2(ua.h2[3]);
      o0.x += pa * a0.x; o0.y += pa * a0.y; o0.z += pa * a1.x; o0.w += pa * a1.y;
      o1.x += pa * a2.x; o1.y += pa * a2.y; o1.z += pa * a3.x; o1.w += pa * a3.y;
      float2 b0 = __half22float2(ub.h2[0]);
      float2 b1 = __half22float2(ub.h2[1]);
      float2 b2 = __half22float2(ub.h2[2]);
      float2 b3 = __half22float2(ub.h2[3]);
      o0.x += pb * b0.x; o0.y += pb * b0.y; o0.z += pb * b1.x; o0.w += pb * b1.y;
      o1.x += pb * b2.x; o1.y += pb * b2.y; o1.z += pb * b3.x; o1.w += pb * b3.y;
    }
  }
#pragma unroll
  for (int off = 1; off < 8; off <<= 1) dsum += __shfl_xor(dsum, off);

  const float inv = 1.f / (dsum + 1e-16f);
  const float4 b0 = ((const float4*)bias)[q * 2];
  const float4 b1 = ((const float4*)bias)[q * 2 + 1];
  float vreg[8];
  vreg[0] = fmaxf(o0.x * inv + b0.x, 0.f);
  vreg[1] = fmaxf(o0.y * inv + b0.y, 0.f);
  vreg[2] = fmaxf(o0.z * inv + b0.z, 0.f);
  vreg[3] = fmaxf(o0.w * inv + b0.w, 0.f);
  vreg[4] = fmaxf(o1.x * inv + b1.x, 0.f);
  vreg[5] = fmaxf(o1.y * inv + b1.y, 0.f);
  vreg[6] = fmaxf(o1.z * inv + b1.z, 0.f);
  vreg[7] = fmaxf(o1.w * inv + b1.w, 0.f);

  __syncthreads();  // swh ready (all threads reach; no early returns above)

  float out8[8] = {0.f, 0.f, 0.f, 0.f, 0.f, 0.f, 0.f, 0.f};
#pragma unroll
  for (int kq = 0; kq < 8; ++kq) {
#pragma unroll
    for (int m = 0; m < 8; ++m) {
      float vb = __shfl(vreg[m], (lane & 56) | kq);
      union { float4 f4; __half2 h2[4]; } uw;
      uw.f4 = *(const float4*)(swh + (kq * 8 + m) * HD + q * 8);
      float2 w0 = __half22float2(uw.h2[0]);
      float2 w1 = __half22float2(uw.h2[1]);
      float2 w2 = __half22float2(uw.h2[2]);
      float2 w3 = __half22float2(uw.h2[3]);
      out8[0] += vb * w0.x; out8[1] += vb * w0.y;
      out8[2] += vb * w1.x; out8[3] += vb * w1.y;
      out8[4] += vb * w2.x; out8[5] += vb * w2.y;
      out8[6] += vb * w3.x; out8[7] += vb * w3.y;
    }
  }

  float ps = 0.f, pd = 0.f;
#pragma unroll
  for (int j = 0; j < 8; ++j) {
    ps += out8[j] * asn[q * 8 + j];
    pd += out8[j] * adn[q * 8 + j];
  }
#pragma unroll
  for (int off = 1; off < 8; off <<= 1) {
    ps += __shfl_xor(ps, off);
    pd += __shfl_xor(pd, off);
  }

  if (!act) return;
  union { float4 f4; __half2 h2[4]; } wv;
  wv.h2[0] = __floats2half2_rn(out8[0], out8[1]);
  wv.h2[1] = __floats2half2_rn(out8[2], out8[3]);
  wv.h2[2] = __floats2half2_rn(out8[4], out8[5]);
  wv.h2[3] = __floats2half2_rn(out8[6], out8[7]);
  ((float4*)(xout + (size_t)n * HD))[q] = wv.f4;
  if (q == 0) { ssrc_out[n] = ps; sdst_out[n] = pd; }
}

// ---------------- final: aggregate + head (val@Wc + bc) ----------------------
template <int TSEL>
__global__ __launch_bounds__(256) void k_agg_head(
    const int* __restrict__ row_ptr, const u64* __restrict__ aos,
    const __half* __restrict__ xin, const float* __restrict__ ssrc_in,
    const float* __restrict__ sdst_in, const float* __restrict__ bias,
    const float* __restrict__ Wc, const float* __restrict__ bc,
    float* __restrict__ outf) {
  const int gw = (blockIdx.x * blockDim.x + threadIdx.x) >> 6;
  const int lane = threadIdx.x & 63;
  const int g = lane >> 3;
  const int q = lane & 7;
  const int n = gw * 8 + g;
  const bool act = n < NN;
  int beg = 0, end = 0;
  float sd = 0.f;
  if (act) { beg = row_ptr[n]; end = row_ptr[n + 1]; sd = sdst_in[n]; }

  float dsum = 0.f;
  float4 o0 = make_float4(0.f, 0.f, 0.f, 0.f);
  float4 o1 = make_float4(0.f, 0.f, 0.f, 0.f);
  for (int base = beg; base < end; base += 16) {
    const int p0 = base + q, p1 = base + 8 + q;
    float pe0 = 0.f, pe1 = 0.f;
    int s0 = 0, s1 = 0;
    if (p0 < end) {
      u64 r = aos[p0];
      s0 = (int)(r & 0xFFFFu);
      float tt = __half2float(__ushort_as_half((u16)((r >> (16 * TSEL)) & 0xFFFFu)));
      float raw = ssrc_in[s0] + sd + tt;
      raw = raw > 0.f ? raw : 0.2f * raw;
      pe0 = __expf(raw);
    }
    if (p1 < end) {
      u64 r = aos[p1];
      s1 = (int)(r & 0xFFFFu);
      float tt = __half2float(__ushort_as_half((u16)((r >> (16 * TSEL)) & 0xFFFFu)));
      float raw = ssrc_in[s1] + sd + tt;
      raw = raw > 0.f ? raw : 0.2f * raw;
      pe1 = __expf(raw);
    }
    dsum += pe0 + pe1;
#pragma unroll
    for (int j = 0; j < 8; ++j) {
      const int sl = g * 8 + j;
      float pa = __shfl(pe0, sl);
      int sa = __shfl(s0, sl);
      float pb = __shfl(pe1, sl);
      int sb = __shfl(s1, sl);
      union { float4 f4; __half2 h2[4]; } ua, ub;
      ua.f4 = ((const float4*)(xin + (size_t)sa * HD))[q];
      ub.f4 = ((const float4*)(xin + (size_t)sb * HD))[q];
      float2 a0 = __half22float2(ua.h2[0]);
      float2 a1 = __half22float2(ua.h2[1]);
      float2 a2 = __half22float2(ua.h2[2]);
      float2 a3 = __half22float2(ua.h2[3]);
      o0.x += pa * a0.x; o0.y += pa * a0.y; o0.z += pa * a1.x; o0.w += pa * a1.y;
      o1.x += pa * a2.x; o1.y += pa * a2.y; o1.z += pa * a3.x; o1.w += pa * a3.y;
      float2 b0 = __half22float2(ub.h2[0]);
      float2 b1 = __half22float2(ub.h2[1]);
      float2 b2 = __half22float2(ub.h2[2]);
      float2 b3 = __half22float2(ub.h2[3]);
      o0.x += pb * b0.x; o0.y += pb * b0.y; o0.z += pb * b1.x; o0.w += pb * b1.y;
      o1.x += pb * b2.x; o1.y += pb * b2.y; o1.z += pb * b3.x; o1.w += pb * b3.y;
    }
  }
#pragma unroll
  for (int off = 1; off < 8; off <<= 1) dsum += __shfl_xor(dsum, off);

  if (!act) return;
  const float inv = 1.f / (dsum + 1e-16f);
  const float4 b0 = ((const float4*)bias)[q * 2];
  const float4 b1 = ((const float4*)bias)[q * 2 + 1];
  const float4 w0 = ((const float4*)Wc)[q * 2];
  const float4 w1 = ((const float4*)Wc)[q * 2 + 1];
  float c = fmaxf(o0.x * inv + b0.x, 0.f) * w0.x +
            fmaxf(o0.y * inv + b0.y, 0.f) * w0.y +
            fmaxf(o0.z * inv + b0.z, 0.f) * w0.z +
            fmaxf(o0.w * inv + b0.w, 0.f) * w0.w +
            fmaxf(o1.x * inv + b1.x, 0.f) * w1.x +
            fmaxf(o1.y * inv + b1.y, 0.f) * w1.y +
            fmaxf(o1.z * inv + b1.z, 0.f) * w1.z +
            fmaxf(o1.w * inv + b1.w, 0.f) * w1.w;
#pragma unroll
  for (int off = 1; off < 8; off <<= 1) c += __shfl_xor(c, off);
  if (q == 0) outf[n] = c + bc[0];
}

// ---------------- host-side orchestration ------------------------------------
extern "C" void kernel_launch(void* const* d_in, const int* in_sizes, int n_in,
                              void* d_out, int out_size, void* d_ws, size_t ws_size,
                              hipStream_t stream) {
  const float* x     = (const float*)d_in[0];
  const int*   ei    = (const int*)d_in[1];
  const float* eattr = (const float*)d_in[2];
  const float* W1  = (const float*)d_in[3];
  const float* We1 = (const float*)d_in[4];
  const float* as1 = (const float*)d_in[5];
  const float* ad1 = (const float*)d_in[6];
  const float* ae1 = (const float*)d_in[7];
  const float* b1  = (const float*)d_in[8];
  const float* W2  = (const float*)d_in[9];
  const float* We2 = (const float*)d_in[10];
  const float* as2 = (const float*)d_in[11];
  const float* ad2 = (const float*)d_in[12];
  const float* ae2 = (const float*)d_in[13];
  const float* b2  = (const float*)d_in[14];
  const float* W3  = (const float*)d_in[15];
  const float* We3 = (const float*)d_in[16];
  const float* as3 = (const float*)d_in[17];
  const float* ad3 = (const float*)d_in[18];
  const float* ae3 = (const float*)d_in[19];
  const float* b3  = (const float*)d_in[20];
  const float* Wc  = (const float*)d_in[21];
  const float* bc  = (const float*)d_in[22];

  const int* srcA = ei;        // edge_index[0]
  const int* dstA = ei + NE;   // edge_index[1]
  float* outf = (float*)d_out;

  char* w = (char*)d_ws;
  auto alloc = [&](size_t bytes) {
    char* p = w;
    w += (bytes + 255) & ~(size_t)255;
    return p;
  };
  float* v123 = (float*)alloc(96 * 4);
  u64* aos = (u64*)alloc((size_t)NE * 8);
  u64* trec = (u64*)alloc((size_t)NE * 8);
  u16* rank = (u16*)alloc((size_t)NE * 2);
  int* row_ptr = (int*)alloc((size_t)(NN + 1) * 4);
  int* deg = (int*)alloc((size_t)NN * 4);
  int* bsum = (int*)alloc((size_t)NB * 4);
  __half* xpA = (__half*)alloc((size_t)NN * HD * 2);
  __half* xpB = (__half*)alloc((size_t)NN * HD * 2);
  float* ssrcA = (float*)alloc((size_t)NN * 4);
  float* sdstA = (float*)alloc((size_t)NN * 4);
  float* ssrcB = (float*)alloc((size_t)NN * 4);
  float* sdstB = (float*)alloc((size_t)NN * 4);

  const int gN = (NN + 255) / 256;
  const int gA = ((NN + 7) / 8 * 64 + 255) / 256;   // 8 nodes per wave

  k_vecs_zero<<<gN, 256, 0, stream>>>(We1, We2, We3, ae1, ae2, ae3, v123, deg);
  // edge scalars + deg atomics fused per-thread, full occupancy, no LDS
  k_edge<<<EB, 256, 0, stream>>>(srcA, dstA, eattr, v123, deg, rank, trec);
  k_scanA<<<NB, 256, 0, stream>>>(deg, bsum);
  k_scanB<<<NB, 256, 0, stream>>>(deg, bsum, row_ptr);
  // layer-1 GEMM (LDS-free) overlapped with CSR scatter
  k_gemm_scatter<<<GP + EB, 256, 0, stream>>>(x, W1, as1, ad1, xpA, ssrcA, sdstA,
                                              dstA, rank, row_ptr, trec, aos);
  // layer 1 aggregate + layer-2 projection (fused)
  k_agg_proj<1><<<gA, 256, 0, stream>>>(row_ptr, aos, xpA, ssrcA, sdstA, b1,
                                        W2, as2, ad2, xpB, ssrcB, sdstB);
  // layer 2 aggregate + layer-3 projection (fused)
  k_agg_proj<2><<<gA, 256, 0, stream>>>(row_ptr, aos, xpB, ssrcB, sdstB, b2,
                                        W3, as3, ad3, xpA, ssrcA, sdstA);
  // layer 3 aggregate + head
  k_agg_head<3><<<gA, 256, 0, stream>>>(row_ptr, aos, xpA, ssrcA, sdstA, b3,
                                        Wc, bc, outf);
}

// Round 2
// 176.118 us; speedup vs baseline: 1.6407x; 1.6407x over previous
//
#include <hip/hip_runtime.h>
#include <hip/hip_fp16.h>
#include <math.h>

#define NN 50000
#define NE 800000
#define FN 128
#define FE 32
#define HD 64
#define NB 49   // scan blocks: ceil(NN/1024)
#define GP ((NN + 127) / 128)   // proj blocks (128 rows each)
#define EB ((NE + 511) / 512)   // edge blocks, 512 edges each (2 per thread)

typedef unsigned long long u64;
typedef unsigned short u16;

// ---------------- K0: fold edge chains into v1,v2,v3 + zero deg --------------
__global__ void k_vecs_zero(const float* __restrict__ We1, const float* __restrict__ We2,
                            const float* __restrict__ We3, const float* __restrict__ ae1,
                            const float* __restrict__ ae2, const float* __restrict__ ae3,
                            float* __restrict__ v123, int* __restrict__ deg) {
  const int i = blockIdx.x * blockDim.x + threadIdx.x;
  if (i < NN) deg[i] = 0;
  if (blockIdx.x != 0) return;
  __shared__ float u2[HD], u3[HD], u23[HD];
  const int t = threadIdx.x;
  if (t < HD) {
    float s2 = 0.f, s3 = 0.f;
    for (int j = 0; j < HD; ++j) {
      s2 += We2[t * HD + j] * ae2[j];
      s3 += We3[t * HD + j] * ae3[j];
    }
    u2[t] = s2; u3[t] = s3;
  }
  __syncthreads();
  if (t < HD) {
    float s23 = 0.f;
    for (int j = 0; j < HD; ++j) s23 += We2[t * HD + j] * u3[j];
    u23[t] = s23;
  }
  __syncthreads();
  if (t < FE) {
    float a = 0.f, b = 0.f, c = 0.f;
    for (int j = 0; j < HD; ++j) {
      float w = We1[t * HD + j];
      a += w * ae1[j];
      b += w * u2[j];
      c += w * u23[j];
    }
    v123[t] = a; v123[32 + t] = b; v123[64 + t] = c;
  }
}

// ---------------- edge scalars -> 8B record ----------------------------------
__device__ __forceinline__ u64 make_trec(const float* __restrict__ eattr,
                                         const float* __restrict__ v123,
                                         int s, int e) {
  const float4* ea = (const float4*)(eattr + (size_t)e * FE);
  float a = 0.f, b = 0.f, c = 0.f;
#pragma unroll
  for (int q = 0; q < FE / 4; ++q) {
    float4 xv = ea[q];
    const float* v1 = v123 + q * 4;
    const float* v2 = v123 + 32 + q * 4;
    const float* v3 = v123 + 64 + q * 4;
    a += xv.x * v1[0] + xv.y * v1[1] + xv.z * v1[2] + xv.w * v1[3];
    b += xv.x * v2[0] + xv.y * v2[1] + xv.z * v2[2] + xv.w * v2[3];
    c += xv.x * v3[0] + xv.y * v3[1] + xv.z * v3[2] + xv.w * v3[3];
  }
  return (u64)(u16)s
       | ((u64)__half_as_ushort(__float2half_rn(a)) << 16)
       | ((u64)__half_as_ushort(__float2half_rn(b)) << 32)
       | ((u64)__half_as_ushort(__float2half_rn(c)) << 48);
}

// ---- k_edge: per-thread fused {deg atomic -> eattr stream -> rank store} ----
// 0 LDS, <=64 VGPR (32 waves/CU). Atomics are issued FIRST (oldest in vmcnt
// queue) so their device-scope round trip hides under 2x 128B eattr compute.
__global__ __launch_bounds__(256, 8) void k_edge(
    const int* __restrict__ srcA, const int* __restrict__ dstA,
    const float* __restrict__ eattr, const float* __restrict__ v123,
    int* __restrict__ deg, u16* __restrict__ rank, u64* __restrict__ trec) {
  const int t = threadIdx.x;
  const int base = blockIdx.x * 512;
  const int e0 = base + t;
  const int e1 = base + 256 + t;
  const bool ok0 = e0 < NE, ok1 = e1 < NE;

  int d0 = 0, d1 = 0, s0 = 0, s1 = 0;
  if (ok0) d0 = dstA[e0];
  if (ok1) d1 = dstA[e1];
  int r0 = 0, r1 = 0;
  if (ok0) r0 = atomicAdd(&deg[d0], 1);   // in flight during stream below
  if (ok1) r1 = atomicAdd(&deg[d1], 1);
  if (ok0) s0 = srcA[e0];
  if (ok1) s1 = srcA[e1];

  if (ok0) trec[e0] = make_trec(eattr, v123, s0, e0);
  if (ok1) trec[e1] = make_trec(eattr, v123, s1, e1);

  if (ok0) rank[e0] = (u16)r0;
  if (ok1) rank[e1] = (u16)r1;
}

// ---------------- 2-phase parallel scan --------------------------------------
__global__ __launch_bounds__(256) void k_scanA(const int* __restrict__ deg,
                                               int* __restrict__ bsum) {
  __shared__ int ws[4];
  const int t = threadIdx.x, lane = t & 63, wid = t >> 6;
  const int i0 = blockIdx.x * 1024 + t * 4;
  int s = 0;
#pragma unroll
  for (int j = 0; j < 4; ++j) {
    int i = i0 + j;
    if (i < NN) s += deg[i];
  }
#pragma unroll
  for (int off = 32; off; off >>= 1) s += __shfl_xor(s, off);
  if (lane == 0) ws[wid] = s;
  __syncthreads();
  if (t == 0) bsum[blockIdx.x] = ws[0] + ws[1] + ws[2] + ws[3];
}

__global__ __launch_bounds__(256) void k_scanB(const int* __restrict__ deg,
                                               const int* __restrict__ bsum,
                                               int* __restrict__ row_ptr) {
  __shared__ int blockOff;
  __shared__ int wOff[4];
  const int b = blockIdx.x;
  const int t = threadIdx.x, lane = t & 63, wid = t >> 6;
  if (t < 64) {
    int v = (t < NB) ? bsum[t] : 0;
    int p = v;
#pragma unroll
    for (int off = 1; off < 64; off <<= 1) {
      int u = __shfl_up(p, off);
      if (lane >= off) p += u;
    }
    if (t == b) blockOff = p - v;
    if (b == 0 && t == NB - 1) row_ptr[NN] = p;
  }
  __syncthreads();
  const int i0 = b * 1024 + t * 4;
  int v[4];
#pragma unroll
  for (int j = 0; j < 4; ++j) {
    int i = i0 + j;
    v[j] = (i < NN) ? deg[i] : 0;
  }
  int s = v[0] + v[1] + v[2] + v[3];
  int p = s;
#pragma unroll
  for (int off = 1; off < 64; off <<= 1) {
    int u = __shfl_up(p, off);
    if (lane >= off) p += u;
  }
  if (lane == 63) wOff[wid] = p;
  __syncthreads();
  int woff = 0;
  for (int wq = 0; wq < wid; ++wq) woff += wOff[wq];
  int excl = blockOff + woff + (p - s);
#pragma unroll
  for (int j = 0; j < 4; ++j) {
    int i = i0 + j;
    if (i < NN) row_ptr[i] = excl;
    excl += v[j];
  }
}

// ---- mega2: [0,GP) LDS-free layer-1 GEMM | rest: CSR scatter (2 edges/thr) --
// GEMM reads x via 16-lane-broadcast float4 loads (L1-served) and W as fp32
// float4 (contiguous 256B/wave, L1-resident 32KB): no LDS -> no 32KB tax on
// the scatter blocks, no stage barriers. Scatter overlaps the GEMM on-CU.
// NOTE: plain launch_bounds(256) — the (256,6) min-waves clause capped VGPR
// at 40 and spilled the accumulators to scratch (131 MB WRITE_SIZE, 195 us).
__global__ __launch_bounds__(256) void k_gemm_scatter(
    const float* __restrict__ x, const float* __restrict__ W,
    const float* __restrict__ asv, const float* __restrict__ adv,
    __half* __restrict__ xph, float* __restrict__ ssrc, float* __restrict__ sdst,
    const int* __restrict__ dstA, const u16* __restrict__ rank,
    const int* __restrict__ row_ptr, const u64* __restrict__ trec,
    u64* __restrict__ aos) {
  const int t = threadIdx.x;
  if (blockIdx.x >= GP) {
    const int base = (blockIdx.x - GP) * 512;
    const int e0 = base + t;
    const int e1 = base + 256 + t;
    if (e0 < NE) aos[row_ptr[dstA[e0]] + (int)rank[e0]] = trec[e0];
    if (e1 < NE) aos[row_ptr[dstA[e1]] + (int)rank[e1]] = trec[e1];
    return;
  }
  // ---- proj part (F = FN = 128, fp32 x, fp32 W) ----
  const int w = t >> 6, l = t & 63;
  const int g = w * 4 + (l >> 4);
  const int rr = g * 8;
  const int c0 = (l & 15) * 4;
  const int row0 = blockIdx.x * 128;

  int xoff[8];   // element offsets, tail rows clamped to a valid row (stores guarded)
#pragma unroll
  for (int i = 0; i < 8; ++i) {
    int gr = row0 + rr + i;
    xoff[i] = (gr < NN ? gr : NN - 1) * FN;
  }

  float acc[8][4];
#pragma unroll
  for (int i = 0; i < 8; ++i)
#pragma unroll
    for (int j = 0; j < 4; ++j) acc[i][j] = 0.f;

  for (int k = 0; k < FN; k += 4) {
    float wv[4][4];
#pragma unroll
    for (int kk = 0; kk < 4; ++kk) {
      float4 wq = *(const float4*)(W + (k + kk) * HD + c0);
      wv[kk][0] = wq.x; wv[kk][1] = wq.y; wv[kk][2] = wq.z; wv[kk][3] = wq.w;
    }
#pragma unroll
    for (int i = 0; i < 8; ++i) {
      float4 a = *(const float4*)(x + xoff[i] + k);
#pragma unroll
      for (int j = 0; j < 4; ++j)
        acc[i][j] += a.x * wv[0][j] + a.y * wv[1][j] + a.z * wv[2][j] + a.w * wv[3][j];
    }
  }

  float as4[4], ad4[4];
#pragma unroll
  for (int j = 0; j < 4; ++j) { as4[j] = asv[c0 + j]; ad4[j] = adv[c0 + j]; }
#pragma unroll
  for (int i = 0; i < 8; ++i) {
    int gr = row0 + rr + i;
    float ps = 0.f, pd = 0.f;
#pragma unroll
    for (int j = 0; j < 4; ++j) {
      ps += acc[i][j] * as4[j];
      pd += acc[i][j] * ad4[j];
    }
#pragma unroll
    for (int off = 1; off < 16; off <<= 1) {
      ps += __shfl_xor(ps, off);
      pd += __shfl_xor(pd, off);
    }
    if (gr < NN) {
      union { __half2 h2[2]; float2 f2; } u;
      u.h2[0] = __floats2half2_rn(acc[i][0], acc[i][1]);
      u.h2[1] = __floats2half2_rn(acc[i][2], acc[i][3]);
      *(float2*)(xph + (size_t)gr * HD + c0) = u.f2;
      if ((l & 15) == 0) { ssrc[gr] = ps; sdst[gr] = pd; }
    }
  }
}

// ------ fused: segment-softmax aggregate + NEXT-layer projection -------------
// 8 nodes per wave, 8 lanes per node (R11/R14 winning layout), chunk=16.
template <int TSEL>
__global__ __launch_bounds__(256) void k_agg_proj(
    const int* __restrict__ row_ptr, const u64* __restrict__ aos,
    const __half* __restrict__ xin, const float* __restrict__ ssrc_in,
    const float* __restrict__ sdst_in, const float* __restrict__ bias,
    const float* __restrict__ Wn, const float* __restrict__ asn,
    const float* __restrict__ adn, __half* __restrict__ xout,
    float* __restrict__ ssrc_out, float* __restrict__ sdst_out) {
  __shared__ __half swh[HD * HD];  // 8 KB, next-layer W in fp16
  const int t = threadIdx.x;
  for (int i = t; i < HD * HD; i += 256) swh[i] = __float2half_rn(Wn[i]);

  const int gw = (blockIdx.x * blockDim.x + t) >> 6;
  const int lane = t & 63;
  const int g = lane >> 3;
  const int q = lane & 7;
  const int n = gw * 8 + g;
  const bool act = n < NN;
  int beg = 0, end = 0;
  float sd = 0.f;
  if (act) { beg = row_ptr[n]; end = row_ptr[n + 1]; sd = sdst_in[n]; }

  float dsum = 0.f;
  float4 o0 = make_float4(0.f, 0.f, 0.f, 0.f);
  float4 o1 = make_float4(0.f, 0.f, 0.f, 0.f);
  for (int base = beg; base < end; base += 16) {
    const int p0 = base + q, p1 = base + 8 + q;
    float pe0 = 0.f, pe1 = 0.f;
    int s0 = 0, s1 = 0;
    if (p0 < end) {
      u64 r = aos[p0];
      s0 = (int)(r & 0xFFFFu);
      float tt = __half2float(__ushort_as_half((u16)((r >> (16 * TSEL)) & 0xFFFFu)));
      float raw = ssrc_in[s0] + sd + tt;
      raw = raw > 0.f ? raw : 0.2f * raw;
      pe0 = __expf(raw);
    }
    if (p1 < end) {
      u64 r = aos[p1];
      s1 = (int)(r & 0xFFFFu);
      float tt = __half2float(__ushort_as_half((u16)((r >> (16 * TSEL)) & 0xFFFFu)));
      float raw = ssrc_in[s1] + sd + tt;
      raw = raw > 0.f ? raw : 0.2f * raw;
      pe1 = __expf(raw);
    }
    dsum += pe0 + pe1;
#pragma unroll
    for (int j = 0; j < 8; ++j) {
      const int sl = g * 8 + j;
      float pa = __shfl(pe0, sl);
      int sa = __shfl(s0, sl);
      float pb = __shfl(pe1, sl);
      int sb = __shfl(s1, sl);
      union { float4 f4; __half2 h2[4]; } ua, ub;
      ua.f4 = ((const float4*)(xin + (size_t)sa * HD))[q];
      ub.f4 = ((const float4*)(xin + (size_t)sb * HD))[q];
      float2 a0 = __half22float2(ua.h2[0]);
      float2 a1 = __half22float2(ua.h2[1]);
      float2 a2 = __half22float2(ua.h2[2]);
      float2 a3 = __half22float2(ua.h2[3]);
      o0.x += pa * a0.x; o0.y += pa * a0.y; o0.z += pa * a1.x; o0.w += pa * a1.y;
      o1.x += pa * a2.x; o1.y += pa * a2.y; o1.z += pa * a3.x; o1.w += pa * a3.y;
      float2 b0 = __half22float2(ub.h2[0]);
      float2 b1 = __half22float2(ub.h2[1]);
      float2 b2 = __half22float2(ub.h2[2]);
      float2 b3 = __half22float2(ub.h2[3]);
      o0.x += pb * b0.x; o0.y += pb * b0.y; o0.z += pb * b1.x; o0.w += pb * b1.y;
      o1.x += pb * b2.x; o1.y += pb * b2.y; o1.z += pb * b3.x; o1.w += pb * b3.y;
    }
  }
#pragma unroll
  for (int off = 1; off < 8; off <<= 1) dsum += __shfl_xor(dsum, off);

  const float inv = 1.f / (dsum + 1e-16f);
  const float4 b0 = ((const float4*)bias)[q * 2];
  const float4 b1 = ((const float4*)bias)[q * 2 + 1];
  float vreg[8];
  vreg[0] = fmaxf(o0.x * inv + b0.x, 0.f);
  vreg[1] = fmaxf(o0.y * inv + b0.y, 0.f);
  vreg[2] = fmaxf(o0.z * inv + b0.z, 0.f);
  vreg[3] = fmaxf(o0.w * inv + b0.w, 0.f);
  vreg[4] = fmaxf(o1.x * inv + b1.x, 0.f);
  vreg[5] = fmaxf(o1.y * inv + b1.y, 0.f);
  vreg[6] = fmaxf(o1.z * inv + b1.z, 0.f);
  vreg[7] = fmaxf(o1.w * inv + b1.w, 0.f);

  __syncthreads();  // swh ready (all threads reach; no early returns above)

  float out8[8] = {0.f, 0.f, 0.f, 0.f, 0.f, 0.f, 0.f, 0.f};
#pragma unroll
  for (int kq = 0; kq < 8; ++kq) {
#pragma unroll
    for (int m = 0; m < 8; ++m) {
      float vb = __shfl(vreg[m], (lane & 56) | kq);
      union { float4 f4; __half2 h2[4]; } uw;
      uw.f4 = *(const float4*)(swh + (kq * 8 + m) * HD + q * 8);
      float2 w0 = __half22float2(uw.h2[0]);
      float2 w1 = __half22float2(uw.h2[1]);
      float2 w2 = __half22float2(uw.h2[2]);
      float2 w3 = __half22float2(uw.h2[3]);
      out8[0] += vb * w0.x; out8[1] += vb * w0.y;
      out8[2] += vb * w1.x; out8[3] += vb * w1.y;
      out8[4] += vb * w2.x; out8[5] += vb * w2.y;
      out8[6] += vb * w3.x; out8[7] += vb * w3.y;
    }
  }

  float ps = 0.f, pd = 0.f;
#pragma unroll
  for (int j = 0; j < 8; ++j) {
    ps += out8[j] * asn[q * 8 + j];
    pd += out8[j] * adn[q * 8 + j];
  }
#pragma unroll
  for (int off = 1; off < 8; off <<= 1) {
    ps += __shfl_xor(ps, off);
    pd += __shfl_xor(pd, off);
  }

  if (!act) return;
  union { float4 f4; __half2 h2[4]; } wv;
  wv.h2[0] = __floats2half2_rn(out8[0], out8[1]);
  wv.h2[1] = __floats2half2_rn(out8[2], out8[3]);
  wv.h2[2] = __floats2half2_rn(out8[4], out8[5]);
  wv.h2[3] = __floats2half2_rn(out8[6], out8[7]);
  ((float4*)(xout + (size_t)n * HD))[q] = wv.f4;
  if (q == 0) { ssrc_out[n] = ps; sdst_out[n] = pd; }
}

// ---------------- final: aggregate + head (val@Wc + bc) ----------------------
template <int TSEL>
__global__ __launch_bounds__(256) void k_agg_head(
    const int* __restrict__ row_ptr, const u64* __restrict__ aos,
    const __half* __restrict__ xin, const float* __restrict__ ssrc_in,
    const float* __restrict__ sdst_in, const float* __restrict__ bias,
    const float* __restrict__ Wc, const float* __restrict__ bc,
    float* __restrict__ outf) {
  const int gw = (blockIdx.x * blockDim.x + threadIdx.x) >> 6;
  const int lane = threadIdx.x & 63;
  const int g = lane >> 3;
  const int q = lane & 7;
  const int n = gw * 8 + g;
  const bool act = n < NN;
  int beg = 0, end = 0;
  float sd = 0.f;
  if (act) { beg = row_ptr[n]; end = row_ptr[n + 1]; sd = sdst_in[n]; }

  float dsum = 0.f;
  float4 o0 = make_float4(0.f, 0.f, 0.f, 0.f);
  float4 o1 = make_float4(0.f, 0.f, 0.f, 0.f);
  for (int base = beg; base < end; base += 16) {
    const int p0 = base + q, p1 = base + 8 + q;
    float pe0 = 0.f, pe1 = 0.f;
    int s0 = 0, s1 = 0;
    if (p0 < end) {
      u64 r = aos[p0];
      s0 = (int)(r & 0xFFFFu);
      float tt = __half2float(__ushort_as_half((u16)((r >> (16 * TSEL)) & 0xFFFFu)));
      float raw = ssrc_in[s0] + sd + tt;
      raw = raw > 0.f ? raw : 0.2f * raw;
      pe0 = __expf(raw);
    }
    if (p1 < end) {
      u64 r = aos[p1];
      s1 = (int)(r & 0xFFFFu);
      float tt = __half2float(__ushort_as_half((u16)((r >> (16 * TSEL)) & 0xFFFFu)));
      float raw = ssrc_in[s1] + sd + tt;
      raw = raw > 0.f ? raw : 0.2f * raw;
      pe1 = __expf(raw);
    }
    dsum += pe0 + pe1;
#pragma unroll
    for (int j = 0; j < 8; ++j) {
      const int sl = g * 8 + j;
      float pa = __shfl(pe0, sl);
      int sa = __shfl(s0, sl);
      float pb = __shfl(pe1, sl);
      int sb = __shfl(s1, sl);
      union { float4 f4; __half2 h2[4]; } ua, ub;
      ua.f4 = ((const float4*)(xin + (size_t)sa * HD))[q];
      ub.f4 = ((const float4*)(xin + (size_t)sb * HD))[q];
      float2 a0 = __half22float2(ua.h2[0]);
      float2 a1 = __half22float2(ua.h2[1]);
      float2 a2 = __half22float2(ua.h2[2]);
      float2 a3 = __half22float2(ua.h2[3]);
      o0.x += pa * a0.x; o0.y += pa * a0.y; o0.z += pa * a1.x; o0.w += pa * a1.y;
      o1.x += pa * a2.x; o1.y += pa * a2.y; o1.z += pa * a3.x; o1.w += pa * a3.y;
      float2 b0 = __half22float2(ub.h2[0]);
      float2 b1 = __half22float2(ub.h2[1]);
      float2 b2 = __half22float2(ub.h2[2]);
      float2 b3 = __half22float2(ub.h2[3]);
      o0.x += pb * b0.x; o0.y += pb * b0.y; o0.z += pb * b1.x; o0.w += pb * b1.y;
      o1.x += pb * b2.x; o1.y += pb * b2.y; o1.z += pb * b3.x; o1.w += pb * b3.y;
    }
  }
#pragma unroll
  for (int off = 1; off < 8; off <<= 1) dsum += __shfl_xor(dsum, off);

  if (!act) return;
  const float inv = 1.f / (dsum + 1e-16f);
  const float4 b0 = ((const float4*)bias)[q * 2];
  const float4 b1 = ((const float4*)bias)[q * 2 + 1];
  const float4 w0 = ((const float4*)Wc)[q * 2];
  const float4 w1 = ((const float4*)Wc)[q * 2 + 1];
  float c = fmaxf(o0.x * inv + b0.x, 0.f) * w0.x +
            fmaxf(o0.y * inv + b0.y, 0.f) * w0.y +
            fmaxf(o0.z * inv + b0.z, 0.f) * w0.z +
            fmaxf(o0.w * inv + b0.w, 0.f) * w0.w +
            fmaxf(o1.x * inv + b1.x, 0.f) * w1.x +
            fmaxf(o1.y * inv + b1.y, 0.f) * w1.y +
            fmaxf(o1.z * inv + b1.z, 0.f) * w1.z +
            fmaxf(o1.w * inv + b1.w, 0.f) * w1.w;
#pragma unroll
  for (int off = 1; off < 8; off <<= 1) c += __shfl_xor(c, off);
  if (q == 0) outf[n] = c + bc[0];
}

// ---------------- host-side orchestration ------------------------------------
extern "C" void kernel_launch(void* const* d_in, const int* in_sizes, int n_in,
                              void* d_out, int out_size, void* d_ws, size_t ws_size,
                              hipStream_t stream) {
  const float* x     = (const float*)d_in[0];
  const int*   ei    = (const int*)d_in[1];
  const float* eattr = (const float*)d_in[2];
  const float* W1  = (const float*)d_in[3];
  const float* We1 = (const float*)d_in[4];
  const float* as1 = (const float*)d_in[5];
  const float* ad1 = (const float*)d_in[6];
  const float* ae1 = (const float*)d_in[7];
  const float* b1  = (const float*)d_in[8];
  const float* W2  = (const float*)d_in[9];
  const float* We2 = (const float*)d_in[10];
  const float* as2 = (const float*)d_in[11];
  const float* ad2 = (const float*)d_in[12];
  const float* ae2 = (const float*)d_in[13];
  const float* b2  = (const float*)d_in[14];
  const float* W3  = (const float*)d_in[15];
  const float* We3 = (const float*)d_in[16];
  const float* as3 = (const float*)d_in[17];
  const float* ad3 = (const float*)d_in[18];
  const float* ae3 = (const float*)d_in[19];
  const float* b3  = (const float*)d_in[20];
  const float* Wc  = (const float*)d_in[21];
  const float* bc  = (const float*)d_in[22];

  const int* srcA = ei;        // edge_index[0]
  const int* dstA = ei + NE;   // edge_index[1]
  float* outf = (float*)d_out;

  char* w = (char*)d_ws;
  auto alloc = [&](size_t bytes) {
    char* p = w;
    w += (bytes + 255) & ~(size_t)255;
    return p;
  };
  float* v123 = (float*)alloc(96 * 4);
  u64* aos = (u64*)alloc((size_t)NE * 8);
  u64* trec = (u64*)alloc((size_t)NE * 8);
  u16* rank = (u16*)alloc((size_t)NE * 2);
  int* row_ptr = (int*)alloc((size_t)(NN + 1) * 4);
  int* deg = (int*)alloc((size_t)NN * 4);
  int* bsum = (int*)alloc((size_t)NB * 4);
  __half* xpA = (__half*)alloc((size_t)NN * HD * 2);
  __half* xpB = (__half*)alloc((size_t)NN * HD * 2);
  float* ssrcA = (float*)alloc((size_t)NN * 4);
  float* sdstA = (float*)alloc((size_t)NN * 4);
  float* ssrcB = (float*)alloc((size_t)NN * 4);
  float* sdstB = (float*)alloc((size_t)NN * 4);

  const int gN = (NN + 255) / 256;
  const int gA = ((NN + 7) / 8 * 64 + 255) / 256;   // 8 nodes per wave

  k_vecs_zero<<<gN, 256, 0, stream>>>(We1, We2, We3, ae1, ae2, ae3, v123, deg);
  // edge scalars + deg atomics fused per-thread, full occupancy, no LDS
  k_edge<<<EB, 256, 0, stream>>>(srcA, dstA, eattr, v123, deg, rank, trec);
  k_scanA<<<NB, 256, 0, stream>>>(deg, bsum);
  k_scanB<<<NB, 256, 0, stream>>>(deg, bsum, row_ptr);
  // layer-1 GEMM (LDS-free) overlapped with CSR scatter
  k_gemm_scatter<<<GP + EB, 256, 0, stream>>>(x, W1, as1, ad1, xpA, ssrcA, sdstA,
                                              dstA, rank, row_ptr, trec, aos);
  // layer 1 aggregate + layer-2 projection (fused)
  k_agg_proj<1><<<gA, 256, 0, stream>>>(row_ptr, aos, xpA, ssrcA, sdstA, b1,
                                        W2, as2, ad2, xpB, ssrcB, sdstB);
  // layer 2 aggregate + layer-3 projection (fused)
  k_agg_proj<2><<<gA, 256, 0, stream>>>(row_ptr, aos, xpB, ssrcB, sdstB, b2,
                                        W3, as3, ad3, xpA, ssrcA, sdstA);
  // layer 3 aggregate + head
  k_agg_head<3><<<gA, 256, 0, stream>>>(row_ptr, aos, xpA, ssrcA, sdstA, b3,
                                        Wc, bc, outf);
}

// Round 3
// 172.332 us; speedup vs baseline: 1.6767x; 1.0220x over previous
//
#include <hip/hip_runtime.h>
#include <hip/hip_fp16.h>
#include <math.h>

#define NN 50000
#define NE 800000
#define FN 128
#define FE 32
#define HD 64
#define NS 16   // degree-histogram shards (cuts same-address atomic chains ~16x)
#define NB 49   // scan blocks: ceil(NN/1024)
#define GP ((NN + 127) / 128)   // proj blocks (128 rows each)
#define EB ((NE + 511) / 512)   // edge blocks, 512 edges each (2 per thread)

typedef unsigned long long u64;
typedef unsigned short u16;

// ---------------- K0: fold edge chains into v1,v2,v3 + zero sharded deg ------
__global__ void k_vecs_zero(const float* __restrict__ We1, const float* __restrict__ We2,
                            const float* __restrict__ We3, const float* __restrict__ ae1,
                            const float* __restrict__ ae2, const float* __restrict__ ae3,
                            float* __restrict__ v123, int* __restrict__ deg) {
  const int i = blockIdx.x * blockDim.x + threadIdx.x;
  if (i < NS * NN) deg[i] = 0;
  if (blockIdx.x != 0) return;
  __shared__ float u2[HD], u3[HD], u23[HD];
  const int t = threadIdx.x;
  if (t < HD) {
    float s2 = 0.f, s3 = 0.f;
    for (int j = 0; j < HD; ++j) {
      s2 += We2[t * HD + j] * ae2[j];
      s3 += We3[t * HD + j] * ae3[j];
    }
    u2[t] = s2; u3[t] = s3;
  }
  __syncthreads();
  if (t < HD) {
    float s23 = 0.f;
    for (int j = 0; j < HD; ++j) s23 += We2[t * HD + j] * u3[j];
    u23[t] = s23;
  }
  __syncthreads();
  if (t < FE) {
    float a = 0.f, b = 0.f, c = 0.f;
    for (int j = 0; j < HD; ++j) {
      float w = We1[t * HD + j];
      a += w * ae1[j];
      b += w * u2[j];
      c += w * u23[j];
    }
    v123[t] = a; v123[32 + t] = b; v123[64 + t] = c;
  }
}

// ---------------- edge scalars -> 8B record ----------------------------------
__device__ __forceinline__ u64 make_trec(const float* __restrict__ eattr,
                                         const float* __restrict__ v123,
                                         int s, int e) {
  const float4* ea = (const float4*)(eattr + (size_t)e * FE);
  float a = 0.f, b = 0.f, c = 0.f;
#pragma unroll
  for (int q = 0; q < FE / 4; ++q) {
    float4 xv = ea[q];
    const float* v1 = v123 + q * 4;
    const float* v2 = v123 + 32 + q * 4;
    const float* v3 = v123 + 64 + q * 4;
    a += xv.x * v1[0] + xv.y * v1[1] + xv.z * v1[2] + xv.w * v1[3];
    b += xv.x * v2[0] + xv.y * v2[1] + xv.z * v2[2] + xv.w * v2[3];
    c += xv.x * v3[0] + xv.y * v3[1] + xv.z * v3[2] + xv.w * v3[3];
  }
  return (u64)(u16)s
       | ((u64)__half_as_ushort(__float2half_rn(a)) << 16)
       | ((u64)__half_as_ushort(__float2half_rn(b)) << 32)
       | ((u64)__half_as_ushort(__float2half_rn(c)) << 48);
}

// ---- mega2: [0,GP) LDS-free layer-1 GEMM | rest: edge {sharded atomic, trec}
// R0 evidence: GEMM rides free under the ~70us atomic floor when co-dispatched.
// Edge shard p = edge-block-index & (NS-1): same-dst atomic chains drop ~16x.
__global__ __launch_bounds__(256) void k_mega2(
    const float* __restrict__ x, const float* __restrict__ W,
    const float* __restrict__ asv, const float* __restrict__ adv,
    __half* __restrict__ xph, float* __restrict__ ssrc, float* __restrict__ sdst,
    const int* __restrict__ srcA, const int* __restrict__ dstA,
    const float* __restrict__ eattr, const float* __restrict__ v123,
    int* __restrict__ deg, u16* __restrict__ rank, u64* __restrict__ trec) {
  const int t = threadIdx.x;
  if (blockIdx.x >= GP) {
    const int k = blockIdx.x - GP;          // edge-block index, 0..EB-1
    const int base = k * 512;
    const int psh = (k & (NS - 1)) * NN;    // shard offset
    const int e0 = base + t;
    const int e1 = base + 256 + t;
    const bool ok0 = e0 < NE, ok1 = e1 < NE;

    int d0 = 0, d1 = 0, s0 = 0, s1 = 0;
    if (ok0) d0 = dstA[e0];
    if (ok1) d1 = dstA[e1];
    int r0 = 0, r1 = 0;
    if (ok0) r0 = atomicAdd(&deg[psh + d0], 1);   // in flight during stream
    if (ok1) r1 = atomicAdd(&deg[psh + d1], 1);
    if (ok0) s0 = srcA[e0];
    if (ok1) s1 = srcA[e1];

    if (ok0) trec[e0] = make_trec(eattr, v123, s0, e0);
    if (ok1) trec[e1] = make_trec(eattr, v123, s1, e1);

    if (ok0) rank[e0] = (u16)r0;
    if (ok1) rank[e1] = (u16)r1;
    return;
  }
  // ---- proj part (F = FN = 128, fp32 x, fp32 W; no LDS, no barriers) ----
  const int w = t >> 6, l = t & 63;
  const int g = w * 4 + (l >> 4);
  const int rr = g * 8;
  const int c0 = (l & 15) * 4;
  const int row0 = blockIdx.x * 128;

  int xoff[8];   // element offsets, tail rows clamped (stores guarded)
#pragma unroll
  for (int i = 0; i < 8; ++i) {
    int gr = row0 + rr + i;
    xoff[i] = (gr < NN ? gr : NN - 1) * FN;
  }

  float acc[8][4];
#pragma unroll
  for (int i = 0; i < 8; ++i)
#pragma unroll
    for (int j = 0; j < 4; ++j) acc[i][j] = 0.f;

  for (int k = 0; k < FN; k += 4) {
    float wv[4][4];
#pragma unroll
    for (int kk = 0; kk < 4; ++kk) {
      float4 wq = *(const float4*)(W + (k + kk) * HD + c0);
      wv[kk][0] = wq.x; wv[kk][1] = wq.y; wv[kk][2] = wq.z; wv[kk][3] = wq.w;
    }
#pragma unroll
    for (int i = 0; i < 8; ++i) {
      float4 a = *(const float4*)(x + xoff[i] + k);
#pragma unroll
      for (int j = 0; j < 4; ++j)
        acc[i][j] += a.x * wv[0][j] + a.y * wv[1][j] + a.z * wv[2][j] + a.w * wv[3][j];
    }
  }

  float as4[4], ad4[4];
#pragma unroll
  for (int j = 0; j < 4; ++j) { as4[j] = asv[c0 + j]; ad4[j] = adv[c0 + j]; }
#pragma unroll
  for (int i = 0; i < 8; ++i) {
    int gr = row0 + rr + i;
    float ps = 0.f, pd = 0.f;
#pragma unroll
    for (int j = 0; j < 4; ++j) {
      ps += acc[i][j] * as4[j];
      pd += acc[i][j] * ad4[j];
    }
#pragma unroll
    for (int off = 1; off < 16; off <<= 1) {
      ps += __shfl_xor(ps, off);
      pd += __shfl_xor(pd, off);
    }
    if (gr < NN) {
      union { __half2 h2[2]; float2 f2; } u;
      u.h2[0] = __floats2half2_rn(acc[i][0], acc[i][1]);
      u.h2[1] = __floats2half2_rn(acc[i][2], acc[i][3]);
      *(float2*)(xph + (size_t)gr * HD + c0) = u.f2;
      if ((l & 15) == 0) { ssrc[gr] = ps; sdst[gr] = pd; }
    }
  }
}

// ---------------- 2-phase parallel scan over shard-summed degrees ------------
__global__ __launch_bounds__(256) void k_scanA(const int* __restrict__ deg,
                                               int* __restrict__ bsum) {
  __shared__ int ws[4];
  const int t = threadIdx.x, lane = t & 63, wid = t >> 6;
  const int i0 = blockIdx.x * 1024 + t * 4;
  int s = 0;
  if (i0 < NN) {   // NN%4==0 so whole int4 in bounds
#pragma unroll
    for (int p = 0; p < NS; ++p) {
      int4 v = *(const int4*)(deg + p * NN + i0);
      s += v.x + v.y + v.z + v.w;
    }
  }
#pragma unroll
  for (int off = 32; off; off >>= 1) s += __shfl_xor(s, off);
  if (lane == 0) ws[wid] = s;
  __syncthreads();
  if (t == 0) bsum[blockIdx.x] = ws[0] + ws[1] + ws[2] + ws[3];
}

// scanB: row_ptr = exclusive prefix of node totals; then deg is rewritten
// IN PLACE to per-(shard,node) scatter bases: deg[p][n] <- row_ptr[n]+prefix.
__global__ __launch_bounds__(256) void k_scanB(int* __restrict__ deg,
                                               const int* __restrict__ bsum,
                                               int* __restrict__ row_ptr) {
  __shared__ int blockOff;
  __shared__ int wOff[4];
  const int b = blockIdx.x;
  const int t = threadIdx.x, lane = t & 63, wid = t >> 6;
  if (t < 64) {
    int v = (t < NB) ? bsum[t] : 0;
    int p = v;
#pragma unroll
    for (int off = 1; off < 64; off <<= 1) {
      int u = __shfl_up(p, off);
      if (lane >= off) p += u;
    }
    if (t == b) blockOff = p - v;
    if (b == 0 && t == NB - 1) row_ptr[NN] = p;
  }
  __syncthreads();
  const int i0 = b * 1024 + t * 4;
  int v[4];
  if (i0 < NN) {
    int4 acc = make_int4(0, 0, 0, 0);
#pragma unroll
    for (int p = 0; p < NS; ++p) {
      int4 dv = *(const int4*)(deg + p * NN + i0);
      acc.x += dv.x; acc.y += dv.y; acc.z += dv.z; acc.w += dv.w;
    }
    v[0] = acc.x; v[1] = acc.y; v[2] = acc.z; v[3] = acc.w;
  } else {
    v[0] = v[1] = v[2] = v[3] = 0;
  }
  int s = v[0] + v[1] + v[2] + v[3];
  int p = s;
#pragma unroll
  for (int off = 1; off < 64; off <<= 1) {
    int u = __shfl_up(p, off);
    if (lane >= off) p += u;
  }
  if (lane == 63) wOff[wid] = p;
  __syncthreads();
  int woff = 0;
  for (int wq = 0; wq < wid; ++wq) woff += wOff[wq];
  int excl = blockOff + woff + (p - s);
#pragma unroll
  for (int j = 0; j < 4; ++j) {
    int i = i0 + j;
    if (i < NN) {
      row_ptr[i] = excl;
      int run = excl;
#pragma unroll
      for (int ps = 0; ps < NS; ++ps) {
        int dv = deg[ps * NN + i];
        deg[ps * NN + i] = run;   // becomes sbase[ps][i]
        run += dv;
      }
      excl += v[j];
    }
  }
}

// ---------------- light scatter: coalesced reads -> one random 8B write ------
// sbase == deg rewritten by scanB; shard from edge-block index (same mapping
// as mega2: 512-edge blocks).
__global__ void k_scatter(const int* __restrict__ dstA, const u16* __restrict__ rank,
                          const int* __restrict__ sbase, const u64* __restrict__ trec,
                          u64* __restrict__ aos) {
  const int k = blockIdx.x;
  const int base = k * 512;
  const int psh = (k & (NS - 1)) * NN;
  const int t = threadIdx.x;
  const int e0 = base + t;
  const int e1 = base + 256 + t;
  if (e0 < NE) aos[sbase[psh + dstA[e0]] + (int)rank[e0]] = trec[e0];
  if (e1 < NE) aos[sbase[psh + dstA[e1]] + (int)rank[e1]] = trec[e1];
}

// ------ fused: segment-softmax aggregate + NEXT-layer projection -------------
// 8 nodes per wave, 8 lanes per node (R11/R14 winning layout), chunk=16.
template <int TSEL>
__global__ __launch_bounds__(256) void k_agg_proj(
    const int* __restrict__ row_ptr, const u64* __restrict__ aos,
    const __half* __restrict__ xin, const float* __restrict__ ssrc_in,
    const float* __restrict__ sdst_in, const float* __restrict__ bias,
    const float* __restrict__ Wn, const float* __restrict__ asn,
    const float* __restrict__ adn, __half* __restrict__ xout,
    float* __restrict__ ssrc_out, float* __restrict__ sdst_out) {
  __shared__ __half swh[HD * HD];  // 8 KB, next-layer W in fp16
  const int t = threadIdx.x;
  for (int i = t; i < HD * HD; i += 256) swh[i] = __float2half_rn(Wn[i]);

  const int gw = (blockIdx.x * blockDim.x + t) >> 6;
  const int lane = t & 63;
  const int g = lane >> 3;
  const int q = lane & 7;
  const int n = gw * 8 + g;
  const bool act = n < NN;
  int beg = 0, end = 0;
  float sd = 0.f;
  if (act) { beg = row_ptr[n]; end = row_ptr[n + 1]; sd = sdst_in[n]; }

  float dsum = 0.f;
  float4 o0 = make_float4(0.f, 0.f, 0.f, 0.f);
  float4 o1 = make_float4(0.f, 0.f, 0.f, 0.f);
  for (int base = beg; base < end; base += 16) {
    const int p0 = base + q, p1 = base + 8 + q;
    float pe0 = 0.f, pe1 = 0.f;
    int s0 = 0, s1 = 0;
    if (p0 < end) {
      u64 r = aos[p0];
      s0 = (int)(r & 0xFFFFu);
      float tt = __half2float(__ushort_as_half((u16)((r >> (16 * TSEL)) & 0xFFFFu)));
      float raw = ssrc_in[s0] + sd + tt;
      raw = raw > 0.f ? raw : 0.2f * raw;
      pe0 = __expf(raw);
    }
    if (p1 < end) {
      u64 r = aos[p1];
      s1 = (int)(r & 0xFFFFu);
      float tt = __half2float(__ushort_as_half((u16)((r >> (16 * TSEL)) & 0xFFFFu)));
      float raw = ssrc_in[s1] + sd + tt;
      raw = raw > 0.f ? raw : 0.2f * raw;
      pe1 = __expf(raw);
    }
    dsum += pe0 + pe1;
#pragma unroll
    for (int j = 0; j < 8; ++j) {
      const int sl = g * 8 + j;
      float pa = __shfl(pe0, sl);
      int sa = __shfl(s0, sl);
      float pb = __shfl(pe1, sl);
      int sb = __shfl(s1, sl);
      union { float4 f4; __half2 h2[4]; } ua, ub;
      ua.f4 = ((const float4*)(xin + (size_t)sa * HD))[q];
      ub.f4 = ((const float4*)(xin + (size_t)sb * HD))[q];
      float2 a0 = __half22float2(ua.h2[0]);
      float2 a1 = __half22float2(ua.h2[1]);
      float2 a2 = __half22float2(ua.h2[2]);
      float2 a3 = __half22float2(ua.h2[3]);
      o0.x += pa * a0.x; o0.y += pa * a0.y; o0.z += pa * a1.x; o0.w += pa * a1.y;
      o1.x += pa * a2.x; o1.y += pa * a2.y; o1.z += pa * a3.x; o1.w += pa * a3.y;
      float2 b0 = __half22float2(ub.h2[0]);
      float2 b1 = __half22float2(ub.h2[1]);
      float2 b2 = __half22float2(ub.h2[2]);
      float2 b3 = __half22float2(ub.h2[3]);
      o0.x += pb * b0.x; o0.y += pb * b0.y; o0.z += pb * b1.x; o0.w += pb * b1.y;
      o1.x += pb * b2.x; o1.y += pb * b2.y; o1.z += pb * b3.x; o1.w += pb * b3.y;
    }
  }
#pragma unroll
  for (int off = 1; off < 8; off <<= 1) dsum += __shfl_xor(dsum, off);

  const float inv = 1.f / (dsum + 1e-16f);
  const float4 b0 = ((const float4*)bias)[q * 2];
  const float4 b1 = ((const float4*)bias)[q * 2 + 1];
  float vreg[8];
  vreg[0] = fmaxf(o0.x * inv + b0.x, 0.f);
  vreg[1] = fmaxf(o0.y * inv + b0.y, 0.f);
  vreg[2] = fmaxf(o0.z * inv + b0.z, 0.f);
  vreg[3] = fmaxf(o0.w * inv + b0.w, 0.f);
  vreg[4] = fmaxf(o1.x * inv + b1.x, 0.f);
  vreg[5] = fmaxf(o1.y * inv + b1.y, 0.f);
  vreg[6] = fmaxf(o1.z * inv + b1.z, 0.f);
  vreg[7] = fmaxf(o1.w * inv + b1.w, 0.f);

  __syncthreads();  // swh ready (all threads reach; no early returns above)

  float out8[8] = {0.f, 0.f, 0.f, 0.f, 0.f, 0.f, 0.f, 0.f};
#pragma unroll
  for (int kq = 0; kq < 8; ++kq) {
#pragma unroll
    for (int m = 0; m < 8; ++m) {
      float vb = __shfl(vreg[m], (lane & 56) | kq);
      union { float4 f4; __half2 h2[4]; } uw;
      uw.f4 = *(const float4*)(swh + (kq * 8 + m) * HD + q * 8);
      float2 w0 = __half22float2(uw.h2[0]);
      float2 w1 = __half22float2(uw.h2[1]);
      float2 w2 = __half22float2(uw.h2[2]);
      float2 w3 = __half22float2(uw.h2[3]);
      out8[0] += vb * w0.x; out8[1] += vb * w0.y;
      out8[2] += vb * w1.x; out8[3] += vb * w1.y;
      out8[4] += vb * w2.x; out8[5] += vb * w2.y;
      out8[6] += vb * w3.x; out8[7] += vb * w3.y;
    }
  }

  float ps = 0.f, pd = 0.f;
#pragma unroll
  for (int j = 0; j < 8; ++j) {
    ps += out8[j] * asn[q * 8 + j];
    pd += out8[j] * adn[q * 8 + j];
  }
#pragma unroll
  for (int off = 1; off < 8; off <<= 1) {
    ps += __shfl_xor(ps, off);
    pd += __shfl_xor(pd, off);
  }

  if (!act) return;
  union { float4 f4; __half2 h2[4]; } wv;
  wv.h2[0] = __floats2half2_rn(out8[0], out8[1]);
  wv.h2[1] = __floats2half2_rn(out8[2], out8[3]);
  wv.h2[2] = __floats2half2_rn(out8[4], out8[5]);
  wv.h2[3] = __floats2half2_rn(out8[6], out8[7]);
  ((float4*)(xout + (size_t)n * HD))[q] = wv.f4;
  if (q == 0) { ssrc_out[n] = ps; sdst_out[n] = pd; }
}

// ---------------- final: aggregate + head (val@Wc + bc) ----------------------
template <int TSEL>
__global__ __launch_bounds__(256) void k_agg_head(
    const int* __restrict__ row_ptr, const u64* __restrict__ aos,
    const __half* __restrict__ xin, const float* __restrict__ ssrc_in,
    const float* __restrict__ sdst_in, const float* __restrict__ bias,
    const float* __restrict__ Wc, const float* __restrict__ bc,
    float* __restrict__ outf) {
  const int gw = (blockIdx.x * blockDim.x + threadIdx.x) >> 6;
  const int lane = threadIdx.x & 63;
  const int g = lane >> 3;
  const int q = lane & 7;
  const int n = gw * 8 + g;
  const bool act = n < NN;
  int beg = 0, end = 0;
  float sd = 0.f;
  if (act) { beg = row_ptr[n]; end = row_ptr[n + 1]; sd = sdst_in[n]; }

  float dsum = 0.f;
  float4 o0 = make_float4(0.f, 0.f, 0.f, 0.f);
  float4 o1 = make_float4(0.f, 0.f, 0.f, 0.f);
  for (int base = beg; base < end; base += 16) {
    const int p0 = base + q, p1 = base + 8 + q;
    float pe0 = 0.f, pe1 = 0.f;
    int s0 = 0, s1 = 0;
    if (p0 < end) {
      u64 r = aos[p0];
      s0 = (int)(r & 0xFFFFu);
      float tt = __half2float(__ushort_as_half((u16)((r >> (16 * TSEL)) & 0xFFFFu)));
      float raw = ssrc_in[s0] + sd + tt;
      raw = raw > 0.f ? raw : 0.2f * raw;
      pe0 = __expf(raw);
    }
    if (p1 < end) {
      u64 r = aos[p1];
      s1 = (int)(r & 0xFFFFu);
      float tt = __half2float(__ushort_as_half((u16)((r >> (16 * TSEL)) & 0xFFFFu)));
      float raw = ssrc_in[s1] + sd + tt;
      raw = raw > 0.f ? raw : 0.2f * raw;
      pe1 = __expf(raw);
    }
    dsum += pe0 + pe1;
#pragma unroll
    for (int j = 0; j < 8; ++j) {
      const int sl = g * 8 + j;
      float pa = __shfl(pe0, sl);
      int sa = __shfl(s0, sl);
      float pb = __shfl(pe1, sl);
      int sb = __shfl(s1, sl);
      union { float4 f4; __half2 h2[4]; } ua, ub;
      ua.f4 = ((const float4*)(xin + (size_t)sa * HD))[q];
      ub.f4 = ((const float4*)(xin + (size_t)sb * HD))[q];
      float2 a0 = __half22float2(ua.h2[0]);
      float2 a1 = __half22float2(ua.h2[1]);
      float2 a2 = __half22float2(ua.h2[2]);
      float2 a3 = __half22float2(ua.h2[3]);
      o0.x += pa * a0.x; o0.y += pa * a0.y; o0.z += pa * a1.x; o0.w += pa * a1.y;
      o1.x += pa * a2.x; o1.y += pa * a2.y; o1.z += pa * a3.x; o1.w += pa * a3.y;
      float2 b0 = __half22float2(ub.h2[0]);
      float2 b1 = __half22float2(ub.h2[1]);
      float2 b2 = __half22float2(ub.h2[2]);
      float2 b3 = __half22float2(ub.h2[3]);
      o0.x += pb * b0.x; o0.y += pb * b0.y; o0.z += pb * b1.x; o0.w += pb * b1.y;
      o1.x += pb * b2.x; o1.y += pb * b2.y; o1.z += pb * b3.x; o1.w += pb * b3.y;
    }
  }
#pragma unroll
  for (int off = 1; off < 8; off <<= 1) dsum += __shfl_xor(dsum, off);

  if (!act) return;
  const float inv = 1.f / (dsum + 1e-16f);
  const float4 b0 = ((const float4*)bias)[q * 2];
  const float4 b1 = ((const float4*)bias)[q * 2 + 1];
  const float4 w0 = ((const float4*)Wc)[q * 2];
  const float4 w1 = ((const float4*)Wc)[q * 2 + 1];
  float c = fmaxf(o0.x * inv + b0.x, 0.f) * w0.x +
            fmaxf(o0.y * inv + b0.y, 0.f) * w0.y +
            fmaxf(o0.z * inv + b0.z, 0.f) * w0.z +
            fmaxf(o0.w * inv + b0.w, 0.f) * w0.w +
            fmaxf(o1.x * inv + b1.x, 0.f) * w1.x +
            fmaxf(o1.y * inv + b1.y, 0.f) * w1.y +
            fmaxf(o1.z * inv + b1.z, 0.f) * w1.z +
            fmaxf(o1.w * inv + b1.w, 0.f) * w1.w;
#pragma unroll
  for (int off = 1; off < 8; off <<= 1) c += __shfl_xor(c, off);
  if (q == 0) outf[n] = c + bc[0];
}

// ---------------- host-side orchestration ------------------------------------
extern "C" void kernel_launch(void* const* d_in, const int* in_sizes, int n_in,
                              void* d_out, int out_size, void* d_ws, size_t ws_size,
                              hipStream_t stream) {
  const float* x     = (const float*)d_in[0];
  const int*   ei    = (const int*)d_in[1];
  const float* eattr = (const float*)d_in[2];
  const float* W1  = (const float*)d_in[3];
  const float* We1 = (const float*)d_in[4];
  const float* as1 = (const float*)d_in[5];
  const float* ad1 = (const float*)d_in[6];
  const float* ae1 = (const float*)d_in[7];
  const float* b1  = (const float*)d_in[8];
  const float* W2  = (const float*)d_in[9];
  const float* We2 = (const float*)d_in[10];
  const float* as2 = (const float*)d_in[11];
  const float* ad2 = (const float*)d_in[12];
  const float* ae2 = (const float*)d_in[13];
  const float* b2  = (const float*)d_in[14];
  const float* W3  = (const float*)d_in[15];
  const float* We3 = (const float*)d_in[16];
  const float* as3 = (const float*)d_in[17];
  const float* ad3 = (const float*)d_in[18];
  const float* ae3 = (const float*)d_in[19];
  const float* b3  = (const float*)d_in[20];
  const float* Wc  = (const float*)d_in[21];
  const float* bc  = (const float*)d_in[22];

  const int* srcA = ei;        // edge_index[0]
  const int* dstA = ei + NE;   // edge_index[1]
  float* outf = (float*)d_out;

  char* w = (char*)d_ws;
  auto alloc = [&](size_t bytes) {
    char* p = w;
    w += (bytes + 255) & ~(size_t)255;
    return p;
  };
  float* v123 = (float*)alloc(96 * 4);
  u64* aos = (u64*)alloc((size_t)NE * 8);
  u64* trec = (u64*)alloc((size_t)NE * 8);
  u16* rank = (u16*)alloc((size_t)NE * 2);
  int* row_ptr = (int*)alloc((size_t)(NN + 1) * 4);
  int* deg = (int*)alloc((size_t)NS * NN * 4);   // sharded; scanB rewrites to sbase
  int* bsum = (int*)alloc((size_t)NB * 4);
  __half* xpA = (__half*)alloc((size_t)NN * HD * 2);
  __half* xpB = (__half*)alloc((size_t)NN * HD * 2);
  float* ssrcA = (float*)alloc((size_t)NN * 4);
  float* sdstA = (float*)alloc((size_t)NN * 4);
  float* ssrcB = (float*)alloc((size_t)NN * 4);
  float* sdstB = (float*)alloc((size_t)NN * 4);

  const int gZ = (NS * NN + 255) / 256;
  const int gA = ((NN + 7) / 8 * 64 + 255) / 256;   // 8 nodes per wave

  k_vecs_zero<<<gZ, 256, 0, stream>>>(We1, We2, We3, ae1, ae2, ae3, v123, deg);
  // layer-1 GEMM + edge {sharded deg atomic, trec stream}, one dispatch
  k_mega2<<<GP + EB, 256, 0, stream>>>(x, W1, as1, ad1, xpA, ssrcA, sdstA,
                                       srcA, dstA, eattr, v123, deg, rank, trec);
  k_scanA<<<NB, 256, 0, stream>>>(deg, bsum);
  k_scanB<<<NB, 256, 0, stream>>>(deg, bsum, row_ptr);
  k_scatter<<<EB, 256, 0, stream>>>(dstA, rank, deg, trec, aos);
  // layer 1 aggregate + layer-2 projection (fused)
  k_agg_proj<1><<<gA, 256, 0, stream>>>(row_ptr, aos, xpA, ssrcA, sdstA, b1,
                                        W2, as2, ad2, xpB, ssrcB, sdstB);
  // layer 2 aggregate + layer-3 projection (fused)
  k_agg_proj<2><<<gA, 256, 0, stream>>>(row_ptr, aos, xpB, ssrcB, sdstB, b2,
                                        W3, as3, ad3, xpA, ssrcA, sdstA);
  // layer 3 aggregate + head
  k_agg_head<3><<<gA, 256, 0, stream>>>(row_ptr, aos, xpA, ssrcA, sdstA, b3,
                                        Wc, bc, outf);
}

// Round 4
// 171.273 us; speedup vs baseline: 1.6871x; 1.0062x over previous
//
#include <hip/hip_runtime.h>
#include <hip/hip_fp16.h>
#include <math.h>

#define NN 50000
#define NE 800000
#define FN 128
#define FE 32
#define HD 64
#define NBKT 196                     // coarse buckets: dst >> 8
#define EPB 2048                     // edges per sort block
#define NSB ((NE + EPB - 1) / EPB)   // 391 sort blocks
#define EPT (EPB / 256)              // 8 edges per thread
#define CNT_N (NBKT * NSB)           // 76,636 count-matrix entries
#define SCB 2048                     // scan elems per block
#define NB2 ((CNT_N + SCB - 1) / SCB) // 38 scan blocks (<=64 for wave scan)
#define GP ((NN + 127) / 128)        // proj blocks (128 rows each)

typedef unsigned long long u64;
typedef unsigned short u16;

// ---------------- edge scalars -> 8B record ----------------------------------
__device__ __forceinline__ u64 make_trec(const float* __restrict__ eattr,
                                         const float* __restrict__ v123,
                                         int s, int e) {
  const float4* ea = (const float4*)(eattr + (size_t)e * FE);
  float a = 0.f, b = 0.f, c = 0.f;
#pragma unroll
  for (int q = 0; q < FE / 4; ++q) {
    float4 xv = ea[q];
    const float* v1 = v123 + q * 4;
    const float* v2 = v123 + 32 + q * 4;
    const float* v3 = v123 + 64 + q * 4;
    a += xv.x * v1[0] + xv.y * v1[1] + xv.z * v1[2] + xv.w * v1[3];
    b += xv.x * v2[0] + xv.y * v2[1] + xv.z * v2[2] + xv.w * v2[3];
    c += xv.x * v3[0] + xv.y * v3[1] + xv.z * v3[2] + xv.w * v3[3];
  }
  return (u64)(u16)s
       | ((u64)__half_as_ushort(__float2half_rn(a)) << 16)
       | ((u64)__half_as_ushort(__float2half_rn(b)) << 32)
       | ((u64)__half_as_ushort(__float2half_rn(c)) << 48);
}

// ---- K1: per-block coarse histogram (LDS atomics only) + v123 fold in blk 0 -
__global__ __launch_bounds__(256) void k_count(
    const int* __restrict__ dstA, int* __restrict__ cnt,
    const float* __restrict__ We1, const float* __restrict__ We2,
    const float* __restrict__ We3, const float* __restrict__ ae1,
    const float* __restrict__ ae2, const float* __restrict__ ae3,
    float* __restrict__ v123) {
  __shared__ int hist[NBKT];
  const int t = threadIdx.x;
  const int blk = blockIdx.x;
  if (t < NBKT) hist[t] = 0;
  __syncthreads();
  const int base = blk * EPB;
#pragma unroll 1
  for (int it = 0; it < EPT; ++it) {
    int e = base + it * 256 + t;
    if (e < NE) atomicAdd(&hist[dstA[e] >> 8], 1);
  }
  __syncthreads();
  if (t < NBKT) cnt[t * NSB + blk] = hist[t];   // bucket-major count matrix

  if (blk != 0) return;   // block 0 additionally folds edge-weight chains
  __shared__ float u2[HD], u3[HD], u23[HD];
  if (t < HD) {
    float s2 = 0.f, s3 = 0.f;
    for (int j = 0; j < HD; ++j) {
      s2 += We2[t * HD + j] * ae2[j];
      s3 += We3[t * HD + j] * ae3[j];
    }
    u2[t] = s2; u3[t] = s3;
  }
  __syncthreads();
  if (t < HD) {
    float s23 = 0.f;
    for (int j = 0; j < HD; ++j) s23 += We2[t * HD + j] * u3[j];
    u23[t] = s23;
  }
  __syncthreads();
  if (t < FE) {
    float a = 0.f, b = 0.f, c = 0.f;
    for (int j = 0; j < HD; ++j) {
      float w = We1[t * HD + j];
      a += w * ae1[j];
      b += w * u2[j];
      c += w * u23[j];
    }
    v123[t] = a; v123[32 + t] = b; v123[64 + t] = c;
  }
}

// ---------------- 2-phase scan of the 76,636-entry count matrix --------------
__global__ __launch_bounds__(256) void k_scanA2(const int* __restrict__ cnt,
                                                int* __restrict__ bsum) {
  __shared__ int ws[4];
  const int t = threadIdx.x, lane = t & 63, wid = t >> 6;
  const int i0 = blockIdx.x * SCB + t * 8;
  int s = 0;
#pragma unroll
  for (int j = 0; j < 8; ++j) {
    int i = i0 + j;
    if (i < CNT_N) s += cnt[i];
  }
#pragma unroll
  for (int off = 32; off; off >>= 1) s += __shfl_xor(s, off);
  if (lane == 0) ws[wid] = s;
  __syncthreads();
  if (t == 0) bsum[blockIdx.x] = ws[0] + ws[1] + ws[2] + ws[3];
}

// in-place: cnt[i] <- exclusive prefix (bucket-major) == gbase[(b,blk)]
__global__ __launch_bounds__(256) void k_scanB2(int* __restrict__ cnt,
                                                const int* __restrict__ bsum) {
  __shared__ int blockOff;
  __shared__ int wOff[4];
  const int b = blockIdx.x;
  const int t = threadIdx.x, lane = t & 63, wid = t >> 6;
  if (t < 64) {
    int v = (t < NB2) ? bsum[t] : 0;
    int p = v;
#pragma unroll
    for (int off = 1; off < 64; off <<= 1) {
      int u = __shfl_up(p, off);
      if (lane >= off) p += u;
    }
    if (t == b) blockOff = p - v;
  }
  __syncthreads();
  const int i0 = b * SCB + t * 8;
  int v[8];
#pragma unroll
  for (int j = 0; j < 8; ++j) {
    int i = i0 + j;
    v[j] = (i < CNT_N) ? cnt[i] : 0;
  }
  int s = 0;
#pragma unroll
  for (int j = 0; j < 8; ++j) s += v[j];
  int p = s;
#pragma unroll
  for (int off = 1; off < 64; off <<= 1) {
    int u = __shfl_up(p, off);
    if (lane >= off) p += u;
  }
  if (lane == 63) wOff[wid] = p;
  __syncthreads();
  int woff = 0;
  for (int wq = 0; wq < wid; ++wq) woff += wOff[wq];
  int excl = blockOff + woff + (p - s);
#pragma unroll
  for (int j = 0; j < 8; ++j) {
    int i = i0 + j;
    if (i < CNT_N) { cnt[i] = excl; excl += v[j]; }
  }
}

// ---- mega3: [0,NSB) edge trec+bucket-scatter (LDS rank) | rest: layer-1 GEMM
// No global atomics anywhere: slot = gbase[bucket][blk] + LDS returning add.
__global__ __launch_bounds__(256) void k_mega3(
    const float* __restrict__ x, const float* __restrict__ W,
    const float* __restrict__ asv, const float* __restrict__ adv,
    __half* __restrict__ xph, float* __restrict__ ssrc, float* __restrict__ sdst,
    const int* __restrict__ srcA, const int* __restrict__ dstA,
    const float* __restrict__ eattr, const float* __restrict__ v123,
    const int* __restrict__ gbase, u64* __restrict__ btrec,
    u16* __restrict__ bdst) {
  __shared__ int off[NBKT];   // 784 B
  const int t = threadIdx.x;
  if (blockIdx.x < NSB) {
    const int blk = blockIdx.x;
    if (t < NBKT) off[t] = gbase[t * NSB + blk];
    __syncthreads();
    const int base = blk * EPB;
#pragma unroll 1
    for (int it = 0; it < EPT; ++it) {
      int e = base + it * 256 + t;
      if (e < NE) {
        int d = dstA[e];
        int s = srcA[e];
        u64 r = make_trec(eattr, v123, s, e);
        int pos = atomicAdd(&off[d >> 8], 1);   // LDS returning atomic
        btrec[pos] = r;
        bdst[pos] = (u16)(d & 255);
      }
    }
    return;
  }
  // ---- proj part (F = FN = 128, fp32 x, fp32 W; no LDS use, no barriers) ----
  const int pb = blockIdx.x - NSB;
  const int w = t >> 6, l = t & 63;
  const int g = w * 4 + (l >> 4);
  const int rr = g * 8;
  const int c0 = (l & 15) * 4;
  const int row0 = pb * 128;

  int xoff[8];   // element offsets, tail rows clamped (stores guarded)
#pragma unroll
  for (int i = 0; i < 8; ++i) {
    int gr = row0 + rr + i;
    xoff[i] = (gr < NN ? gr : NN - 1) * FN;
  }

  float acc[8][4];
#pragma unroll
  for (int i = 0; i < 8; ++i)
#pragma unroll
    for (int j = 0; j < 4; ++j) acc[i][j] = 0.f;

  for (int k = 0; k < FN; k += 4) {
    float wv[4][4];
#pragma unroll
    for (int kk = 0; kk < 4; ++kk) {
      float4 wq = *(const float4*)(W + (k + kk) * HD + c0);
      wv[kk][0] = wq.x; wv[kk][1] = wq.y; wv[kk][2] = wq.z; wv[kk][3] = wq.w;
    }
#pragma unroll
    for (int i = 0; i < 8; ++i) {
      float4 a = *(const float4*)(x + xoff[i] + k);
#pragma unroll
      for (int j = 0; j < 4; ++j)
        acc[i][j] += a.x * wv[0][j] + a.y * wv[1][j] + a.z * wv[2][j] + a.w * wv[3][j];
    }
  }

  float as4[4], ad4[4];
#pragma unroll
  for (int j = 0; j < 4; ++j) { as4[j] = asv[c0 + j]; ad4[j] = adv[c0 + j]; }
#pragma unroll
  for (int i = 0; i < 8; ++i) {
    int gr = row0 + rr + i;
    float ps = 0.f, pd = 0.f;
#pragma unroll
    for (int j = 0; j < 4; ++j) {
      ps += acc[i][j] * as4[j];
      pd += acc[i][j] * ad4[j];
    }
#pragma unroll
    for (int off2 = 1; off2 < 16; off2 <<= 1) {
      ps += __shfl_xor(ps, off2);
      pd += __shfl_xor(pd, off2);
    }
    if (gr < NN) {
      union { __half2 h2[2]; float2 f2; } u;
      u.h2[0] = __floats2half2_rn(acc[i][0], acc[i][1]);
      u.h2[1] = __floats2half2_rn(acc[i][2], acc[i][3]);
      *(float2*)(xph + (size_t)gr * HD + c0) = u.f2;
      if ((l & 15) == 0) { ssrc[gr] = ps; sdst[gr] = pd; }
    }
  }
}

// ---- K4: per-bucket 256-bin counting sort -> row_ptr + final aos ------------
__global__ __launch_bounds__(256) void k_bucket(
    const int* __restrict__ gbase, const u64* __restrict__ btrec,
    const u16* __restrict__ bdst, int* __restrict__ row_ptr,
    u64* __restrict__ aos) {
  __shared__ int hist[256], off2[256];
  __shared__ int wsum[4];
  const int b = blockIdx.x;
  const int t = threadIdx.x, lane = t & 63, wid = t >> 6;
  const int s = gbase[b * NSB];
  const int e = (b + 1 < NBKT) ? gbase[(b + 1) * NSB] : NE;
  hist[t] = 0;
  __syncthreads();
  for (int p = s + t; p < e; p += 256) atomicAdd(&hist[(int)bdst[p]], 1);
  __syncthreads();
  // exclusive scan of hist[256] across 4 waves
  int v = hist[t];
  int pfx = v;
#pragma unroll
  for (int o = 1; o < 64; o <<= 1) {
    int u = __shfl_up(pfx, o);
    if (lane >= o) pfx += u;
  }
  if (lane == 63) wsum[wid] = pfx;
  __syncthreads();
  int woff = 0;
  for (int wq = 0; wq < wid; ++wq) woff += wsum[wq];
  const int excl = woff + pfx - v;
  off2[t] = excl;
  const int n = b * 256 + t;
  if (n < NN) row_ptr[n] = s + excl;
  if (b == 0 && t == 0) row_ptr[NN] = NE;
  __syncthreads();
  // stable-enough unique scatter within bucket (order within node arbitrary)
  for (int p = s + t; p < e; p += 256) {
    u64 r = btrec[p];
    int d8 = (int)bdst[p];
    int pos = s + atomicAdd(&off2[d8], 1);
    aos[pos] = r;
  }
}

// ------ fused: segment-softmax aggregate + NEXT-layer projection -------------
// 8 nodes per wave, 8 lanes per node (R11/R14 winning layout), chunk=16.
template <int TSEL>
__global__ __launch_bounds__(256) void k_agg_proj(
    const int* __restrict__ row_ptr, const u64* __restrict__ aos,
    const __half* __restrict__ xin, const float* __restrict__ ssrc_in,
    const float* __restrict__ sdst_in, const float* __restrict__ bias,
    const float* __restrict__ Wn, const float* __restrict__ asn,
    const float* __restrict__ adn, __half* __restrict__ xout,
    float* __restrict__ ssrc_out, float* __restrict__ sdst_out) {
  __shared__ __half swh[HD * HD];  // 8 KB, next-layer W in fp16
  const int t = threadIdx.x;
  for (int i = t; i < HD * HD; i += 256) swh[i] = __float2half_rn(Wn[i]);

  const int gw = (blockIdx.x * blockDim.x + t) >> 6;
  const int lane = t & 63;
  const int g = lane >> 3;
  const int q = lane & 7;
  const int n = gw * 8 + g;
  const bool act = n < NN;
  int beg = 0, end = 0;
  float sd = 0.f;
  if (act) { beg = row_ptr[n]; end = row_ptr[n + 1]; sd = sdst_in[n]; }

  float dsum = 0.f;
  float4 o0 = make_float4(0.f, 0.f, 0.f, 0.f);
  float4 o1 = make_float4(0.f, 0.f, 0.f, 0.f);
  for (int base = beg; base < end; base += 16) {
    const int p0 = base + q, p1 = base + 8 + q;
    float pe0 = 0.f, pe1 = 0.f;
    int s0 = 0, s1 = 0;
    if (p0 < end) {
      u64 r = aos[p0];
      s0 = (int)(r & 0xFFFFu);
      float tt = __half2float(__ushort_as_half((u16)((r >> (16 * TSEL)) & 0xFFFFu)));
      float raw = ssrc_in[s0] + sd + tt;
      raw = raw > 0.f ? raw : 0.2f * raw;
      pe0 = __expf(raw);
    }
    if (p1 < end) {
      u64 r = aos[p1];
      s1 = (int)(r & 0xFFFFu);
      float tt = __half2float(__ushort_as_half((u16)((r >> (16 * TSEL)) & 0xFFFFu)));
      float raw = ssrc_in[s1] + sd + tt;
      raw = raw > 0.f ? raw : 0.2f * raw;
      pe1 = __expf(raw);
    }
    dsum += pe0 + pe1;
#pragma unroll
    for (int j = 0; j < 8; ++j) {
      const int sl = g * 8 + j;
      float pa = __shfl(pe0, sl);
      int sa = __shfl(s0, sl);
      float pb = __shfl(pe1, sl);
      int sb = __shfl(s1, sl);
      union { float4 f4; __half2 h2[4]; } ua, ub;
      ua.f4 = ((const float4*)(xin + (size_t)sa * HD))[q];
      ub.f4 = ((const float4*)(xin + (size_t)sb * HD))[q];
      float2 a0 = __half22float2(ua.h2[0]);
      float2 a1 = __half22float2(ua.h2[1]);
      float2 a2 = __half22float2(ua.h2[2]);
      float2 a3 = __half22float2(ua.h2[3]);
      o0.x += pa * a0.x; o0.y += pa * a0.y; o0.z += pa * a1.x; o0.w += pa * a1.y;
      o1.x += pa * a2.x; o1.y += pa * a2.y; o1.z += pa * a3.x; o1.w += pa * a3.y;
      float2 b0 = __half22float2(ub.h2[0]);
      float2 b1 = __half22float2(ub.h2[1]);
      float2 b2 = __half22float2(ub.h2[2]);
      float2 b3 = __half22float2(ub.h2[3]);
      o0.x += pb * b0.x; o0.y += pb * b0.y; o0.z += pb * b1.x; o0.w += pb * b1.y;
      o1.x += pb * b2.x; o1.y += pb * b2.y; o1.z += pb * b3.x; o1.w += pb * b3.y;
    }
  }
#pragma unroll
  for (int off = 1; off < 8; off <<= 1) dsum += __shfl_xor(dsum, off);

  const float inv = 1.f / (dsum + 1e-16f);
  const float4 b0 = ((const float4*)bias)[q * 2];
  const float4 b1 = ((const float4*)bias)[q * 2 + 1];
  float vreg[8];
  vreg[0] = fmaxf(o0.x * inv + b0.x, 0.f);
  vreg[1] = fmaxf(o0.y * inv + b0.y, 0.f);
  vreg[2] = fmaxf(o0.z * inv + b0.z, 0.f);
  vreg[3] = fmaxf(o0.w * inv + b0.w, 0.f);
  vreg[4] = fmaxf(o1.x * inv + b1.x, 0.f);
  vreg[5] = fmaxf(o1.y * inv + b1.y, 0.f);
  vreg[6] = fmaxf(o1.z * inv + b1.z, 0.f);
  vreg[7] = fmaxf(o1.w * inv + b1.w, 0.f);

  __syncthreads();  // swh ready (all threads reach; no early returns above)

  float out8[8] = {0.f, 0.f, 0.f, 0.f, 0.f, 0.f, 0.f, 0.f};
#pragma unroll
  for (int kq = 0; kq < 8; ++kq) {
#pragma unroll
    for (int m = 0; m < 8; ++m) {
      float vb = __shfl(vreg[m], (lane & 56) | kq);
      union { float4 f4; __half2 h2[4]; } uw;
      uw.f4 = *(const float4*)(swh + (kq * 8 + m) * HD + q * 8);
      float2 w0 = __half22float2(uw.h2[0]);
      float2 w1 = __half22float2(uw.h2[1]);
      float2 w2 = __half22float2(uw.h2[2]);
      float2 w3 = __half22float2(uw.h2[3]);
      out8[0] += vb * w0.x; out8[1] += vb * w0.y;
      out8[2] += vb * w1.x; out8[3] += vb * w1.y;
      out8[4] += vb * w2.x; out8[5] += vb * w2.y;
      out8[6] += vb * w3.x; out8[7] += vb * w3.y;
    }
  }

  float ps = 0.f, pd = 0.f;
#pragma unroll
  for (int j = 0; j < 8; ++j) {
    ps += out8[j] * asn[q * 8 + j];
    pd += out8[j] * adn[q * 8 + j];
  }
#pragma unroll
  for (int off = 1; off < 8; off <<= 1) {
    ps += __shfl_xor(ps, off);
    pd += __shfl_xor(pd, off);
  }

  if (!act) return;
  union { float4 f4; __half2 h2[4]; } wv;
  wv.h2[0] = __floats2half2_rn(out8[0], out8[1]);
  wv.h2[1] = __floats2half2_rn(out8[2], out8[3]);
  wv.h2[2] = __floats2half2_rn(out8[4], out8[5]);
  wv.h2[3] = __floats2half2_rn(out8[6], out8[7]);
  ((float4*)(xout + (size_t)n * HD))[q] = wv.f4;
  if (q == 0) { ssrc_out[n] = ps; sdst_out[n] = pd; }
}

// ---------------- final: aggregate + head (val@Wc + bc) ----------------------
template <int TSEL>
__global__ __launch_bounds__(256) void k_agg_head(
    const int* __restrict__ row_ptr, const u64* __restrict__ aos,
    const __half* __restrict__ xin, const float* __restrict__ ssrc_in,
    const float* __restrict__ sdst_in, const float* __restrict__ bias,
    const float* __restrict__ Wc, const float* __restrict__ bc,
    float* __restrict__ outf) {
  const int gw = (blockIdx.x * blockDim.x + threadIdx.x) >> 6;
  const int lane = threadIdx.x & 63;
  const int g = lane >> 3;
  const int q = lane & 7;
  const int n = gw * 8 + g;
  const bool act = n < NN;
  int beg = 0, end = 0;
  float sd = 0.f;
  if (act) { beg = row_ptr[n]; end = row_ptr[n + 1]; sd = sdst_in[n]; }

  float dsum = 0.f;
  float4 o0 = make_float4(0.f, 0.f, 0.f, 0.f);
  float4 o1 = make_float4(0.f, 0.f, 0.f, 0.f);
  for (int base = beg; base < end; base += 16) {
    const int p0 = base + q, p1 = base + 8 + q;
    float pe0 = 0.f, pe1 = 0.f;
    int s0 = 0, s1 = 0;
    if (p0 < end) {
      u64 r = aos[p0];
      s0 = (int)(r & 0xFFFFu);
      float tt = __half2float(__ushort_as_half((u16)((r >> (16 * TSEL)) & 0xFFFFu)));
      float raw = ssrc_in[s0] + sd + tt;
      raw = raw > 0.f ? raw : 0.2f * raw;
      pe0 = __expf(raw);
    }
    if (p1 < end) {
      u64 r = aos[p1];
      s1 = (int)(r & 0xFFFFu);
      float tt = __half2float(__ushort_as_half((u16)((r >> (16 * TSEL)) & 0xFFFFu)));
      float raw = ssrc_in[s1] + sd + tt;
      raw = raw > 0.f ? raw : 0.2f * raw;
      pe1 = __expf(raw);
    }
    dsum += pe0 + pe1;
#pragma unroll
    for (int j = 0; j < 8; ++j) {
      const int sl = g * 8 + j;
      float pa = __shfl(pe0, sl);
      int sa = __shfl(s0, sl);
      float pb = __shfl(pe1, sl);
      int sb = __shfl(s1, sl);
      union { float4 f4; __half2 h2[4]; } ua, ub;
      ua.f4 = ((const float4*)(xin + (size_t)sa * HD))[q];
      ub.f4 = ((const float4*)(xin + (size_t)sb * HD))[q];
      float2 a0 = __half22float2(ua.h2[0]);
      float2 a1 = __half22float2(ua.h2[1]);
      float2 a2 = __half22float2(ua.h2[2]);
      float2 a3 = __half22float2(ua.h2[3]);
      o0.x += pa * a0.x; o0.y += pa * a0.y; o0.z += pa * a1.x; o0.w += pa * a1.y;
      o1.x += pa * a2.x; o1.y += pa * a2.y; o1.z += pa * a3.x; o1.w += pa * a3.y;
      float2 b0 = __half22float2(ub.h2[0]);
      float2 b1 = __half22float2(ub.h2[1]);
      float2 b2 = __half22float2(ub.h2[2]);
      float2 b3 = __half22float2(ub.h2[3]);
      o0.x += pb * b0.x; o0.y += pb * b0.y; o0.z += pb * b1.x; o0.w += pb * b1.y;
      o1.x += pb * b2.x; o1.y += pb * b2.y; o1.z += pb * b3.x; o1.w += pb * b3.y;
    }
  }
#pragma unroll
  for (int off = 1; off < 8; off <<= 1) dsum += __shfl_xor(dsum, off);

  if (!act) return;
  const float inv = 1.f / (dsum + 1e-16f);
  const float4 b0 = ((const float4*)bias)[q * 2];
  const float4 b1 = ((const float4*)bias)[q * 2 + 1];
  const float4 w0 = ((const float4*)Wc)[q * 2];
  const float4 w1 = ((const float4*)Wc)[q * 2 + 1];
  float c = fmaxf(o0.x * inv + b0.x, 0.f) * w0.x +
            fmaxf(o0.y * inv + b0.y, 0.f) * w0.y +
            fmaxf(o0.z * inv + b0.z, 0.f) * w0.z +
            fmaxf(o0.w * inv + b0.w, 0.f) * w0.w +
            fmaxf(o1.x * inv + b1.x, 0.f) * w1.x +
            fmaxf(o1.y * inv + b1.y, 0.f) * w1.y +
            fmaxf(o1.z * inv + b1.z, 0.f) * w1.z +
            fmaxf(o1.w * inv + b1.w, 0.f) * w1.w;
#pragma unroll
  for (int off = 1; off < 8; off <<= 1) c += __shfl_xor(c, off);
  if (q == 0) outf[n] = c + bc[0];
}

// ---------------- host-side orchestration ------------------------------------
extern "C" void kernel_launch(void* const* d_in, const int* in_sizes, int n_in,
                              void* d_out, int out_size, void* d_ws, size_t ws_size,
                              hipStream_t stream) {
  const float* x     = (const float*)d_in[0];
  const int*   ei    = (const int*)d_in[1];
  const float* eattr = (const float*)d_in[2];
  const float* W1  = (const float*)d_in[3];
  const float* We1 = (const float*)d_in[4];
  const float* as1 = (const float*)d_in[5];
  const float* ad1 = (const float*)d_in[6];
  const float* ae1 = (const float*)d_in[7];
  const float* b1  = (const float*)d_in[8];
  const float* W2  = (const float*)d_in[9];
  const float* We2 = (const float*)d_in[10];
  const float* as2 = (const float*)d_in[11];
  const float* ad2 = (const float*)d_in[12];
  const float* ae2 = (const float*)d_in[13];
  const float* b2  = (const float*)d_in[14];
  const float* W3  = (const float*)d_in[15];
  const float* We3 = (const float*)d_in[16];
  const float* as3 = (const float*)d_in[17];
  const float* ad3 = (const float*)d_in[18];
  const float* ae3 = (const float*)d_in[19];
  const float* b3  = (const float*)d_in[20];
  const float* Wc  = (const float*)d_in[21];
  const float* bc  = (const float*)d_in[22];

  const int* srcA = ei;        // edge_index[0]
  const int* dstA = ei + NE;   // edge_index[1]
  float* outf = (float*)d_out;

  char* w = (char*)d_ws;
  auto alloc = [&](size_t bytes) {
    char* p = w;
    w += (bytes + 255) & ~(size_t)255;
    return p;
  };
  float* v123 = (float*)alloc(96 * 4);
  u64* aos = (u64*)alloc((size_t)NE * 8);
  u64* btrec = (u64*)alloc((size_t)NE * 8);
  u16* bdst = (u16*)alloc((size_t)NE * 2);
  int* row_ptr = (int*)alloc((size_t)(NN + 1) * 4);
  int* cnt = (int*)alloc((size_t)CNT_N * 4);
  int* bsum = (int*)alloc((size_t)NB2 * 4);
  __half* xpA = (__half*)alloc((size_t)NN * HD * 2);
  __half* xpB = (__half*)alloc((size_t)NN * HD * 2);
  float* ssrcA = (float*)alloc((size_t)NN * 4);
  float* sdstA = (float*)alloc((size_t)NN * 4);
  float* ssrcB = (float*)alloc((size_t)NN * 4);
  float* sdstB = (float*)alloc((size_t)NN * 4);

  const int gA = ((NN + 7) / 8 * 64 + 255) / 256;   // 8 nodes per wave

  // coarse histogram (LDS atomics) + v123 fold
  k_count<<<NSB, 256, 0, stream>>>(dstA, cnt, We1, We2, We3, ae1, ae2, ae3, v123);
  // exclusive scan of count matrix -> per-(bucket,block) global bases
  k_scanA2<<<NB2, 256, 0, stream>>>(cnt, bsum);
  k_scanB2<<<NB2, 256, 0, stream>>>(cnt, bsum);
  // edge trec + bucket scatter (no global atomics) | layer-1 GEMM co-dispatch
  k_mega3<<<NSB + GP, 256, 0, stream>>>(x, W1, as1, ad1, xpA, ssrcA, sdstA,
                                        srcA, dstA, eattr, v123, cnt, btrec, bdst);
  // per-bucket 256-bin counting sort -> row_ptr + aos
  k_bucket<<<NBKT, 256, 0, stream>>>(cnt, btrec, bdst, row_ptr, aos);
  // layer 1 aggregate + layer-2 projection (fused)
  k_agg_proj<1><<<gA, 256, 0, stream>>>(row_ptr, aos, xpA, ssrcA, sdstA, b1,
                                        W2, as2, ad2, xpB, ssrcB, sdstB);
  // layer 2 aggregate + layer-3 projection (fused)
  k_agg_proj<2><<<gA, 256, 0, stream>>>(row_ptr, aos, xpB, ssrcB, sdstB, b2,
                                        W3, as3, ad3, xpA, ssrcA, sdstA);
  // layer 3 aggregate + head
  k_agg_head<3><<<gA, 256, 0, stream>>>(row_ptr, aos, xpA, ssrcA, sdstA, b3,
                                        Wc, bc, outf);
}

// Round 5
// 151.755 us; speedup vs baseline: 1.9041x; 1.1286x over previous
//
#include <hip/hip_runtime.h>
#include <hip/hip_fp16.h>
#include <math.h>

#define NN 50000
#define NE 800000
#define FN 128
#define FE 32
#define HD 64
#define NB 49   // scan blocks: ceil(NN/1024)
#define GP ((NN + 127) / 128)    // proj blocks (128 rows each)
#define NT (NE / 64)             // 12500 64-edge tiles (NE % 64 == 0)
#define EB2 ((NT + 7) / 8)       // 1563 edge blocks: 4 waves x 2 tiles
#define GE ((NE + 255) / 256)    // scatter blocks

typedef unsigned long long u64;
typedef unsigned short u16;

// ---------------- K0: fold edge chains into v1,v2,v3 + zero deg --------------
__global__ void k_vecs_zero(const float* __restrict__ We1, const float* __restrict__ We2,
                            const float* __restrict__ We3, const float* __restrict__ ae1,
                            const float* __restrict__ ae2, const float* __restrict__ ae3,
                            float* __restrict__ v123, int* __restrict__ deg) {
  const int i = blockIdx.x * blockDim.x + threadIdx.x;
  if (i < NN) deg[i] = 0;
  if (blockIdx.x != 0) return;
  __shared__ float u2[HD], u3[HD], u23[HD];
  const int t = threadIdx.x;
  if (t < HD) {
    float s2 = 0.f, s3 = 0.f;
    for (int j = 0; j < HD; ++j) {
      s2 += We2[t * HD + j] * ae2[j];
      s3 += We3[t * HD + j] * ae3[j];
    }
    u2[t] = s2; u3[t] = s3;
  }
  __syncthreads();
  if (t < HD) {
    float s23 = 0.f;
    for (int j = 0; j < HD; ++j) s23 += We2[t * HD + j] * u3[j];
    u23[t] = s23;
  }
  __syncthreads();
  if (t < FE) {
    float a = 0.f, b = 0.f, c = 0.f;
    for (int j = 0; j < HD; ++j) {
      float w = We1[t * HD + j];
      a += w * ae1[j];
      b += w * u2[j];
      c += w * u23[j];
    }
    v123[t] = a; v123[32 + t] = b; v123[64 + t] = c;
  }
}

// ---- mega4: [0,GP) LDS-free layer-1 GEMM | rest: COALESCED edge phase -------
// Edge tile = 64 edges/wave. 8 lanes cooperate per eattr row (lane q reads
// float4 #q) -> each load instruction covers 1024 CONTIGUOUS bytes (vs the
// 64-line gather of R0-R4 that capped effective BW at ~1.2 TB/s). Dot-reduce
// via shfl_xor(1,2,4) within the 8-lane group; substep k's edge is kept by
// lane q==k, so lane (g,q) ends up owning edge E0+8q+g (bijection) and all
// trec/rank/dst/src accesses are permutations of contiguous windows.
__global__ __launch_bounds__(256) void k_mega4(
    const float* __restrict__ x, const float* __restrict__ W,
    const float* __restrict__ asv, const float* __restrict__ adv,
    __half* __restrict__ xph, float* __restrict__ ssrc, float* __restrict__ sdst,
    const int* __restrict__ srcA, const int* __restrict__ dstA,
    const float* __restrict__ eattr, const float* __restrict__ v123,
    int* __restrict__ deg, u16* __restrict__ rank, u64* __restrict__ trec) {
  const int t = threadIdx.x;
  if (blockIdx.x >= GP) {
    const int kb = blockIdx.x - GP;          // 0 .. EB2-1
    const int w = t >> 6, lane = t & 63;
    const int g = lane >> 3, q = lane & 7;
    const float4 v1q = *(const float4*)(v123 + q * 4);
    const float4 v2q = *(const float4*)(v123 + 32 + q * 4);
    const float4 v3q = *(const float4*)(v123 + 64 + q * 4);
    const int perm = 8 * q + g;              // my owned edge slot within a tile
#pragma unroll
    for (int it = 0; it < 2; ++it) {
      const int tIdx = kb * 8 + w * 2 + it;
      if (tIdx < NT) {
        const int E0 = tIdx * 64;
        const int e = E0 + perm;
        const int d = dstA[e];
        const int s = srcA[e];
        const int r = atomicAdd(&deg[d], 1);   // in flight under gather below
        float ra = 0.f, rb = 0.f, rc = 0.f;
#pragma unroll
        for (int k = 0; k < 8; ++k) {
          const float4 xv =
              *(const float4*)(eattr + (size_t)(E0 + 8 * k + g) * FE + q * 4);
          float a = xv.x * v1q.x + xv.y * v1q.y + xv.z * v1q.z + xv.w * v1q.w;
          float b = xv.x * v2q.x + xv.y * v2q.y + xv.z * v2q.z + xv.w * v2q.w;
          float c = xv.x * v3q.x + xv.y * v3q.y + xv.z * v3q.z + xv.w * v3q.w;
#pragma unroll
          for (int off = 1; off < 8; off <<= 1) {
            a += __shfl_xor(a, off);
            b += __shfl_xor(b, off);
            c += __shfl_xor(c, off);
          }
          if (q == k) { ra = a; rb = b; rc = c; }
        }
        trec[e] = (u64)(u16)s
                | ((u64)__half_as_ushort(__float2half_rn(ra)) << 16)
                | ((u64)__half_as_ushort(__float2half_rn(rb)) << 32)
                | ((u64)__half_as_ushort(__float2half_rn(rc)) << 48);
        rank[e] = (u16)r;
      }
    }
    return;
  }
  // ---- proj part (F = FN = 128, fp32 x, fp32 W; no LDS, no barriers) ----
  const int w = t >> 6, l = t & 63;
  const int g = w * 4 + (l >> 4);
  const int rr = g * 8;
  const int c0 = (l & 15) * 4;
  const int row0 = blockIdx.x * 128;

  int xoff[8];   // element offsets, tail rows clamped (stores guarded)
#pragma unroll
  for (int i = 0; i < 8; ++i) {
    int gr = row0 + rr + i;
    xoff[i] = (gr < NN ? gr : NN - 1) * FN;
  }

  float acc[8][4];
#pragma unroll
  for (int i = 0; i < 8; ++i)
#pragma unroll
    for (int j = 0; j < 4; ++j) acc[i][j] = 0.f;

  for (int k = 0; k < FN; k += 4) {
    float wv[4][4];
#pragma unroll
    for (int kk = 0; kk < 4; ++kk) {
      float4 wq = *(const float4*)(W + (k + kk) * HD + c0);
      wv[kk][0] = wq.x; wv[kk][1] = wq.y; wv[kk][2] = wq.z; wv[kk][3] = wq.w;
    }
#pragma unroll
    for (int i = 0; i < 8; ++i) {
      float4 a = *(const float4*)(x + xoff[i] + k);
#pragma unroll
      for (int j = 0; j < 4; ++j)
        acc[i][j] += a.x * wv[0][j] + a.y * wv[1][j] + a.z * wv[2][j] + a.w * wv[3][j];
    }
  }

  float as4[4], ad4[4];
#pragma unroll
  for (int j = 0; j < 4; ++j) { as4[j] = asv[c0 + j]; ad4[j] = adv[c0 + j]; }
#pragma unroll
  for (int i = 0; i < 8; ++i) {
    int gr = row0 + rr + i;
    float ps = 0.f, pd = 0.f;
#pragma unroll
    for (int j = 0; j < 4; ++j) {
      ps += acc[i][j] * as4[j];
      pd += acc[i][j] * ad4[j];
    }
#pragma unroll
    for (int off = 1; off < 16; off <<= 1) {
      ps += __shfl_xor(ps, off);
      pd += __shfl_xor(pd, off);
    }
    if (gr < NN) {
      union { __half2 h2[2]; float2 f2; } u;
      u.h2[0] = __floats2half2_rn(acc[i][0], acc[i][1]);
      u.h2[1] = __floats2half2_rn(acc[i][2], acc[i][3]);
      *(float2*)(xph + (size_t)gr * HD + c0) = u.f2;
      if ((l & 15) == 0) { ssrc[gr] = ps; sdst[gr] = pd; }
    }
  }
}

// ---------------- 2-phase parallel scan --------------------------------------
__global__ __launch_bounds__(256) void k_scanA(const int* __restrict__ deg,
                                               int* __restrict__ bsum) {
  __shared__ int ws[4];
  const int t = threadIdx.x, lane = t & 63, wid = t >> 6;
  const int i0 = blockIdx.x * 1024 + t * 4;
  int s = 0;
#pragma unroll
  for (int j = 0; j < 4; ++j) {
    int i = i0 + j;
    if (i < NN) s += deg[i];
  }
#pragma unroll
  for (int off = 32; off; off >>= 1) s += __shfl_xor(s, off);
  if (lane == 0) ws[wid] = s;
  __syncthreads();
  if (t == 0) bsum[blockIdx.x] = ws[0] + ws[1] + ws[2] + ws[3];
}

__global__ __launch_bounds__(256) void k_scanB(const int* __restrict__ deg,
                                               const int* __restrict__ bsum,
                                               int* __restrict__ row_ptr) {
  __shared__ int blockOff;
  __shared__ int wOff[4];
  const int b = blockIdx.x;
  const int t = threadIdx.x, lane = t & 63, wid = t >> 6;
  if (t < 64) {
    int v = (t < NB) ? bsum[t] : 0;
    int p = v;
#pragma unroll
    for (int off = 1; off < 64; off <<= 1) {
      int u = __shfl_up(p, off);
      if (lane >= off) p += u;
    }
    if (t == b) blockOff = p - v;
    if (b == 0 && t == NB - 1) row_ptr[NN] = p;
  }
  __syncthreads();
  const int i0 = b * 1024 + t * 4;
  int v[4];
#pragma unroll
  for (int j = 0; j < 4; ++j) {
    int i = i0 + j;
    v[j] = (i < NN) ? deg[i] : 0;
  }
  int s = v[0] + v[1] + v[2] + v[3];
  int p = s;
#pragma unroll
  for (int off = 1; off < 64; off <<= 1) {
    int u = __shfl_up(p, off);
    if (lane >= off) p += u;
  }
  if (lane == 63) wOff[wid] = p;
  __syncthreads();
  int woff = 0;
  for (int wq = 0; wq < wid; ++wq) woff += wOff[wq];
  int excl = blockOff + woff + (p - s);
#pragma unroll
  for (int j = 0; j < 4; ++j) {
    int i = i0 + j;
    if (i < NN) row_ptr[i] = excl;
    excl += v[j];
  }
}

// ---------------- light scatter: coalesced reads -> one random 8B write ------
__global__ void k_scatter(const int* __restrict__ dstA, const u16* __restrict__ rank,
                          const int* __restrict__ row_ptr, const u64* __restrict__ trec,
                          u64* __restrict__ aos) {
  const int e = blockIdx.x * blockDim.x + threadIdx.x;
  if (e >= NE) return;
  aos[row_ptr[dstA[e]] + (int)rank[e]] = trec[e];
}

// ------ fused: segment-softmax aggregate + NEXT-layer projection -------------
// 8 nodes per wave, 8 lanes per node (R11/R14 winning layout), chunk=16.
template <int TSEL>
__global__ __launch_bounds__(256) void k_agg_proj(
    const int* __restrict__ row_ptr, const u64* __restrict__ aos,
    const __half* __restrict__ xin, const float* __restrict__ ssrc_in,
    const float* __restrict__ sdst_in, const float* __restrict__ bias,
    const float* __restrict__ Wn, const float* __restrict__ asn,
    const float* __restrict__ adn, __half* __restrict__ xout,
    float* __restrict__ ssrc_out, float* __restrict__ sdst_out) {
  __shared__ __half swh[HD * HD];  // 8 KB, next-layer W in fp16
  const int t = threadIdx.x;
  for (int i = t; i < HD * HD; i += 256) swh[i] = __float2half_rn(Wn[i]);

  const int gw = (blockIdx.x * blockDim.x + t) >> 6;
  const int lane = t & 63;
  const int g = lane >> 3;
  const int q = lane & 7;
  const int n = gw * 8 + g;
  const bool act = n < NN;
  int beg = 0, end = 0;
  float sd = 0.f;
  if (act) { beg = row_ptr[n]; end = row_ptr[n + 1]; sd = sdst_in[n]; }

  float dsum = 0.f;
  float4 o0 = make_float4(0.f, 0.f, 0.f, 0.f);
  float4 o1 = make_float4(0.f, 0.f, 0.f, 0.f);
  for (int base = beg; base < end; base += 16) {
    const int p0 = base + q, p1 = base + 8 + q;
    float pe0 = 0.f, pe1 = 0.f;
    int s0 = 0, s1 = 0;
    if (p0 < end) {
      u64 r = aos[p0];
      s0 = (int)(r & 0xFFFFu);
      float tt = __half2float(__ushort_as_half((u16)((r >> (16 * TSEL)) & 0xFFFFu)));
      float raw = ssrc_in[s0] + sd + tt;
      raw = raw > 0.f ? raw : 0.2f * raw;
      pe0 = __expf(raw);
    }
    if (p1 < end) {
      u64 r = aos[p1];
      s1 = (int)(r & 0xFFFFu);
      float tt = __half2float(__ushort_as_half((u16)((r >> (16 * TSEL)) & 0xFFFFu)));
      float raw = ssrc_in[s1] + sd + tt;
      raw = raw > 0.f ? raw : 0.2f * raw;
      pe1 = __expf(raw);
    }
    dsum += pe0 + pe1;
#pragma unroll
    for (int j = 0; j < 8; ++j) {
      const int sl = g * 8 + j;
      float pa = __shfl(pe0, sl);
      int sa = __shfl(s0, sl);
      float pb = __shfl(pe1, sl);
      int sb = __shfl(s1, sl);
      union { float4 f4; __half2 h2[4]; } ua, ub;
      ua.f4 = ((const float4*)(xin + (size_t)sa * HD))[q];
      ub.f4 = ((const float4*)(xin + (size_t)sb * HD))[q];
      float2 a0 = __half22float2(ua.h2[0]);
      float2 a1 = __half22float2(ua.h2[1]);
      float2 a2 = __half22float2(ua.h2[2]);
      float2 a3 = __half22float2(ua.h2[3]);
      o0.x += pa * a0.x; o0.y += pa * a0.y; o0.z += pa * a1.x; o0.w += pa * a1.y;
      o1.x += pa * a2.x; o1.y += pa * a2.y; o1.z += pa * a3.x; o1.w += pa * a3.y;
      float2 b0 = __half22float2(ub.h2[0]);
      float2 b1 = __half22float2(ub.h2[1]);
      float2 b2 = __half22float2(ub.h2[2]);
      float2 b3 = __half22float2(ub.h2[3]);
      o0.x += pb * b0.x; o0.y += pb * b0.y; o0.z += pb * b1.x; o0.w += pb * b1.y;
      o1.x += pb * b2.x; o1.y += pb * b2.y; o1.z += pb * b3.x; o1.w += pb * b3.y;
    }
  }
#pragma unroll
  for (int off = 1; off < 8; off <<= 1) dsum += __shfl_xor(dsum, off);

  const float inv = 1.f / (dsum + 1e-16f);
  const float4 b0 = ((const float4*)bias)[q * 2];
  const float4 b1 = ((const float4*)bias)[q * 2 + 1];
  float vreg[8];
  vreg[0] = fmaxf(o0.x * inv + b0.x, 0.f);
  vreg[1] = fmaxf(o0.y * inv + b0.y, 0.f);
  vreg[2] = fmaxf(o0.z * inv + b0.z, 0.f);
  vreg[3] = fmaxf(o0.w * inv + b0.w, 0.f);
  vreg[4] = fmaxf(o1.x * inv + b1.x, 0.f);
  vreg[5] = fmaxf(o1.y * inv + b1.y, 0.f);
  vreg[6] = fmaxf(o1.z * inv + b1.z, 0.f);
  vreg[7] = fmaxf(o1.w * inv + b1.w, 0.f);

  __syncthreads();  // swh ready (all threads reach; no early returns above)

  float out8[8] = {0.f, 0.f, 0.f, 0.f, 0.f, 0.f, 0.f, 0.f};
#pragma unroll
  for (int kq = 0; kq < 8; ++kq) {
#pragma unroll
    for (int m = 0; m < 8; ++m) {
      float vb = __shfl(vreg[m], (lane & 56) | kq);
      union { float4 f4; __half2 h2[4]; } uw;
      uw.f4 = *(const float4*)(swh + (kq * 8 + m) * HD + q * 8);
      float2 w0 = __half22float2(uw.h2[0]);
      float2 w1 = __half22float2(uw.h2[1]);
      float2 w2 = __half22float2(uw.h2[2]);
      float2 w3 = __half22float2(uw.h2[3]);
      out8[0] += vb * w0.x; out8[1] += vb * w0.y;
      out8[2] += vb * w1.x; out8[3] += vb * w1.y;
      out8[4] += vb * w2.x; out8[5] += vb * w2.y;
      out8[6] += vb * w3.x; out8[7] += vb * w3.y;
    }
  }

  float ps = 0.f, pd = 0.f;
#pragma unroll
  for (int j = 0; j < 8; ++j) {
    ps += out8[j] * asn[q * 8 + j];
    pd += out8[j] * adn[q * 8 + j];
  }
#pragma unroll
  for (int off = 1; off < 8; off <<= 1) {
    ps += __shfl_xor(ps, off);
    pd += __shfl_xor(pd, off);
  }

  if (!act) return;
  union { float4 f4; __half2 h2[4]; } wv;
  wv.h2[0] = __floats2half2_rn(out8[0], out8[1]);
  wv.h2[1] = __floats2half2_rn(out8[2], out8[3]);
  wv.h2[2] = __floats2half2_rn(out8[4], out8[5]);
  wv.h2[3] = __floats2half2_rn(out8[6], out8[7]);
  ((float4*)(xout + (size_t)n * HD))[q] = wv.f4;
  if (q == 0) { ssrc_out[n] = ps; sdst_out[n] = pd; }
}

// ---------------- final: aggregate + head (val@Wc + bc) ----------------------
template <int TSEL>
__global__ __launch_bounds__(256) void k_agg_head(
    const int* __restrict__ row_ptr, const u64* __restrict__ aos,
    const __half* __restrict__ xin, const float* __restrict__ ssrc_in,
    const float* __restrict__ sdst_in, const float* __restrict__ bias,
    const float* __restrict__ Wc, const float* __restrict__ bc,
    float* __restrict__ outf) {
  const int gw = (blockIdx.x * blockDim.x + threadIdx.x) >> 6;
  const int lane = threadIdx.x & 63;
  const int g = lane >> 3;
  const int q = lane & 7;
  const int n = gw * 8 + g;
  const bool act = n < NN;
  int beg = 0, end = 0;
  float sd = 0.f;
  if (act) { beg = row_ptr[n]; end = row_ptr[n + 1]; sd = sdst_in[n]; }

  float dsum = 0.f;
  float4 o0 = make_float4(0.f, 0.f, 0.f, 0.f);
  float4 o1 = make_float4(0.f, 0.f, 0.f, 0.f);
  for (int base = beg; base < end; base += 16) {
    const int p0 = base + q, p1 = base + 8 + q;
    float pe0 = 0.f, pe1 = 0.f;
    int s0 = 0, s1 = 0;
    if (p0 < end) {
      u64 r = aos[p0];
      s0 = (int)(r & 0xFFFFu);
      float tt = __half2float(__ushort_as_half((u16)((r >> (16 * TSEL)) & 0xFFFFu)));
      float raw = ssrc_in[s0] + sd + tt;
      raw = raw > 0.f ? raw : 0.2f * raw;
      pe0 = __expf(raw);
    }
    if (p1 < end) {
      u64 r = aos[p1];
      s1 = (int)(r & 0xFFFFu);
      float tt = __half2float(__ushort_as_half((u16)((r >> (16 * TSEL)) & 0xFFFFu)));
      float raw = ssrc_in[s1] + sd + tt;
      raw = raw > 0.f ? raw : 0.2f * raw;
      pe1 = __expf(raw);
    }
    dsum += pe0 + pe1;
#pragma unroll
    for (int j = 0; j < 8; ++j) {
      const int sl = g * 8 + j;
      float pa = __shfl(pe0, sl);
      int sa = __shfl(s0, sl);
      float pb = __shfl(pe1, sl);
      int sb = __shfl(s1, sl);
      union { float4 f4; __half2 h2[4]; } ua, ub;
      ua.f4 = ((const float4*)(xin + (size_t)sa * HD))[q];
      ub.f4 = ((const float4*)(xin + (size_t)sb * HD))[q];
      float2 a0 = __half22float2(ua.h2[0]);
      float2 a1 = __half22float2(ua.h2[1]);
      float2 a2 = __half22float2(ua.h2[2]);
      float2 a3 = __half22float2(ua.h2[3]);
      o0.x += pa * a0.x; o0.y += pa * a0.y; o0.z += pa * a1.x; o0.w += pa * a1.y;
      o1.x += pa * a2.x; o1.y += pa * a2.y; o1.z += pa * a3.x; o1.w += pa * a3.y;
      float2 b0 = __half22float2(ub.h2[0]);
      float2 b1 = __half22float2(ub.h2[1]);
      float2 b2 = __half22float2(ub.h2[2]);
      float2 b3 = __half22float2(ub.h2[3]);
      o0.x += pb * b0.x; o0.y += pb * b0.y; o0.z += pb * b1.x; o0.w += pb * b1.y;
      o1.x += pb * b2.x; o1.y += pb * b2.y; o1.z += pb * b3.x; o1.w += pb * b3.y;
    }
  }
#pragma unroll
  for (int off = 1; off < 8; off <<= 1) dsum += __shfl_xor(dsum, off);

  if (!act) return;
  const float inv = 1.f / (dsum + 1e-16f);
  const float4 b0 = ((const float4*)bias)[q * 2];
  const float4 b1 = ((const float4*)bias)[q * 2 + 1];
  const float4 w0 = ((const float4*)Wc)[q * 2];
  const float4 w1 = ((const float4*)Wc)[q * 2 + 1];
  float c = fmaxf(o0.x * inv + b0.x, 0.f) * w0.x +
            fmaxf(o0.y * inv + b0.y, 0.f) * w0.y +
            fmaxf(o0.z * inv + b0.z, 0.f) * w0.z +
            fmaxf(o0.w * inv + b0.w, 0.f) * w0.w +
            fmaxf(o1.x * inv + b1.x, 0.f) * w1.x +
            fmaxf(o1.y * inv + b1.y, 0.f) * w1.y +
            fmaxf(o1.z * inv + b1.z, 0.f) * w1.z +
            fmaxf(o1.w * inv + b1.w, 0.f) * w1.w;
#pragma unroll
  for (int off = 1; off < 8; off <<= 1) c += __shfl_xor(c, off);
  if (q == 0) outf[n] = c + bc[0];
}

// ---------------- host-side orchestration ------------------------------------
extern "C" void kernel_launch(void* const* d_in, const int* in_sizes, int n_in,
                              void* d_out, int out_size, void* d_ws, size_t ws_size,
                              hipStream_t stream) {
  const float* x     = (const float*)d_in[0];
  const int*   ei    = (const int*)d_in[1];
  const float* eattr = (const float*)d_in[2];
  const float* W1  = (const float*)d_in[3];
  const float* We1 = (const float*)d_in[4];
  const float* as1 = (const float*)d_in[5];
  const float* ad1 = (const float*)d_in[6];
  const float* ae1 = (const float*)d_in[7];
  const float* b1  = (const float*)d_in[8];
  const float* W2  = (const float*)d_in[9];
  const float* We2 = (const float*)d_in[10];
  const float* as2 = (const float*)d_in[11];
  const float* ad2 = (const float*)d_in[12];
  const float* ae2 = (const float*)d_in[13];
  const float* b2  = (const float*)d_in[14];
  const float* W3  = (const float*)d_in[15];
  const float* We3 = (const float*)d_in[16];
  const float* as3 = (const float*)d_in[17];
  const float* ad3 = (const float*)d_in[18];
  const float* ae3 = (const float*)d_in[19];
  const float* b3  = (const float*)d_in[20];
  const float* Wc  = (const float*)d_in[21];
  const float* bc  = (const float*)d_in[22];

  const int* srcA = ei;        // edge_index[0]
  const int* dstA = ei + NE;   // edge_index[1]
  float* outf = (float*)d_out;

  char* w = (char*)d_ws;
  auto alloc = [&](size_t bytes) {
    char* p = w;
    w += (bytes + 255) & ~(size_t)255;
    return p;
  };
  float* v123 = (float*)alloc(96 * 4);
  u64* aos = (u64*)alloc((size_t)NE * 8);
  u64* trec = (u64*)alloc((size_t)NE * 8);
  u16* rank = (u16*)alloc((size_t)NE * 2);
  int* row_ptr = (int*)alloc((size_t)(NN + 1) * 4);
  int* deg = (int*)alloc((size_t)NN * 4);
  int* bsum = (int*)alloc((size_t)NB * 4);
  __half* xpA = (__half*)alloc((size_t)NN * HD * 2);
  __half* xpB = (__half*)alloc((size_t)NN * HD * 2);
  float* ssrcA = (float*)alloc((size_t)NN * 4);
  float* sdstA = (float*)alloc((size_t)NN * 4);
  float* ssrcB = (float*)alloc((size_t)NN * 4);
  float* sdstB = (float*)alloc((size_t)NN * 4);

  const int gN = (NN + 255) / 256;
  const int gA = ((NN + 7) / 8 * 64 + 255) / 256;   // 8 nodes per wave

  k_vecs_zero<<<gN, 256, 0, stream>>>(We1, We2, We3, ae1, ae2, ae3, v123, deg);
  // layer-1 GEMM + coalesced edge {deg atomic, trec stream}, one dispatch
  k_mega4<<<GP + EB2, 256, 0, stream>>>(x, W1, as1, ad1, xpA, ssrcA, sdstA,
                                        srcA, dstA, eattr, v123, deg, rank, trec);
  k_scanA<<<NB, 256, 0, stream>>>(deg, bsum);
  k_scanB<<<NB, 256, 0, stream>>>(deg, bsum, row_ptr);
  k_scatter<<<GE, 256, 0, stream>>>(dstA, rank, row_ptr, trec, aos);
  // layer 1 aggregate + layer-2 projection (fused)
  k_agg_proj<1><<<gA, 256, 0, stream>>>(row_ptr, aos, xpA, ssrcA, sdstA, b1,
                                        W2, as2, ad2, xpB, ssrcB, sdstB);
  // layer 2 aggregate + layer-3 projection (fused)
  k_agg_proj<2><<<gA, 256, 0, stream>>>(row_ptr, aos, xpB, ssrcB, sdstB, b2,
                                        W3, as3, ad3, xpA, ssrcA, sdstA);
  // layer 3 aggregate + head
  k_agg_head<3><<<gA, 256, 0, stream>>>(row_ptr, aos, xpA, ssrcA, sdstA, b3,
                                        Wc, bc, outf);
}